// Round 5
// baseline (1095.344 us; speedup 1.0000x reference)
//
#include <hip/hip_runtime.h>
#include <hip/hip_bf16.h>
#include <math.h>

#define NTOK   4096   // B*T
#define TSEQ   2048
#define DMODEL 1024
#define DINNER 2048
#define NSTATE 16
#define DTRANK 64
#define NEXP   8
#define DFF    2048
#define NCHUNK 32
#define CLEN   64     // TSEQ / NCHUNK

typedef __attribute__((ext_vector_type(8))) short short8;
typedef __attribute__((ext_vector_type(4))) float f32x4;

__device__ __forceinline__ float fast_rcp(float x){ return __builtin_amdgcn_rcpf(x); }
__device__ __forceinline__ float siluf(float x){ return x * fast_rcp(1.f + __expf(-x)); }

// fp32 -> bf16 (round-to-nearest-even), as raw ushort
__device__ __forceinline__ unsigned short f2bf(float x){
  unsigned int u = __float_as_uint(x);
  unsigned int r = (u + 0x7FFFu + ((u >> 16) & 1u)) >> 16;
  return (unsigned short)r;
}

// split fp32 -> (hi, lo) bf16 pair: x ~= hi + lo, |err| <= 2^-18 |x|
__device__ __forceinline__ void split4(float4 a, unsigned short* hi, unsigned short* lo){
  float av[4] = {a.x, a.y, a.z, a.w};
  #pragma unroll
  for (int j=0;j<4;j++){
    unsigned short hu = f2bf(av[j]);
    float hf = __uint_as_float((unsigned int)hu << 16);
    hi[j] = hu;
    lo[j] = f2bf(av[j] - hf);
  }
}

// ---------------------------------------------------------------------------
__global__ void zero_kernel(int* __restrict__ p){ p[threadIdx.x] = 0; }

// ---------------------------------------------------------------------------
// Pre-split fp32 array into hi/lo bf16 arrays. n multiple of 1024.
// ---------------------------------------------------------------------------
__global__ __launch_bounds__(256) void split_kernel(
    const float* __restrict__ in, unsigned short* __restrict__ hi,
    unsigned short* __restrict__ lo, int n)
{
  int i = (blockIdx.x*256 + threadIdx.x)*4;
  if (i >= n) return;
  float4 v = *(const float4*)(in + i);
  unsigned short ht[4], lt[4];
  split4(v, ht, lt);
  uint2 hw, lw;
  hw.x = (unsigned)ht[0] | ((unsigned)ht[1]<<16);
  hw.y = (unsigned)ht[2] | ((unsigned)ht[3]<<16);
  lw.x = (unsigned)lt[0] | ((unsigned)lt[1]<<16);
  lw.y = (unsigned)lt[2] | ((unsigned)lt[3]<<16);
  *(uint2*)(hi+i) = hw;
  *(uint2*)(lo+i) = lw;
}

// fp32 -> bf16 convert (no split). n multiple of 2048.
__global__ __launch_bounds__(256) void cvt_bf_kernel(
    const float* __restrict__ in, unsigned short* __restrict__ out, int n)
{
  int i = (blockIdx.x*256 + threadIdx.x)*8;
  if (i >= n) return;
  float4 a = *(const float4*)(in+i);
  float4 b = *(const float4*)(in+i+4);
  short8 v;
  v[0]=(short)f2bf(a.x); v[1]=(short)f2bf(a.y); v[2]=(short)f2bf(a.z); v[3]=(short)f2bf(a.w);
  v[4]=(short)f2bf(b.x); v[5]=(short)f2bf(b.y); v[6]=(short)f2bf(b.z); v[7]=(short)f2bf(b.w);
  *(short8*)(out+i) = v;
}

// ---------------------------------------------------------------------------
// Split-bf16 MFMA GEMM: C[M,N] = A[M,K] @ W[N,K]^T (+epilogue), ~fp32 accuracy.
// W pre-split (Whi/Wlo). A either pre-split (PS=true) or fp32 (split in-kernel).
// Per product: ah*bh + al*bh + ah*bl (fp32 acc).
// Tile BM x (CT*16), BK=32, 256 threads / 4 waves; wave tile (16*RG) x (CT*16).
// SK=true: K is per-slice, blockIdx.z selects slice; out += z*M*ldo (partials).
// EPI: 0 = +bias | 1 = plain | 2 = +bias,softplus
// ---------------------------------------------------------------------------
template<int EPI, int BM, bool PS, int CT, bool SK>
__global__ __launch_bounds__(256) void gemm_big(
    const float* __restrict__ A,
    const unsigned short* __restrict__ Ahi, const unsigned short* __restrict__ Alo, int lda,
    const unsigned short* __restrict__ Whi, const unsigned short* __restrict__ Wlo, int ldw,
    int M, int N, int K,
    const float* __restrict__ bias,
    float* __restrict__ out, int ldo)
{
  constexpr int BN  = CT*16;
  constexpr int RG  = BM/64;       // 16-row groups per wave
  constexpr int TPR = 256/BM;      // threads per A row
  constexpr int EA  = 32/TPR;      // A elems per thread per ktile
  constexpr int TPW = 256/BN;      // threads per W row
  constexpr int EW  = 32/TPW;      // W elems per thread per ktile
  const int tid = threadIdx.x;
  const int m0 = blockIdx.y * BM;
  const int n0 = blockIdx.x * BN;
  const int koff = SK ? blockIdx.z * K : 0;
  float* outp = out + (SK ? (size_t)blockIdx.z * M * ldo : 0);

  __shared__ __align__(16) unsigned short Ahs[BM*40];
  __shared__ __align__(16) unsigned short Als[BM*40];
  __shared__ __align__(16) unsigned short Whs[BN*40];
  __shared__ __align__(16) unsigned short Wls[BN*40];

  const int arow = tid / TPR;
  const int aseg = (tid % TPR) * EA;
  const int wrow = tid / TPW;
  const int wseg = (tid % TPW) * EW;

  const float* Ap = PS ? nullptr : (A + (size_t)(m0 + arow)*lda + aseg + koff);
  const unsigned short* Aph = PS ? (Ahi + (size_t)(m0 + arow)*lda + aseg + koff) : nullptr;
  const unsigned short* Apl = PS ? (Alo + (size_t)(m0 + arow)*lda + aseg + koff) : nullptr;
  const bool wok = (n0 + wrow) < N;
  const unsigned short* Whp = Whi + (size_t)(n0 + wrow)*ldw + wseg + koff;
  const unsigned short* Wlp = Wlo + (size_t)(n0 + wrow)*ldw + wseg + koff;

  const int lane = tid & 63;
  const int wv   = tid >> 6;
  const int qd   = lane >> 4;
  const int mr   = lane & 15;

  f32x4 acc[RG][CT];
  #pragma unroll
  for (int rg=0; rg<RG; rg++)
    #pragma unroll
    for (int ct=0; ct<CT; ct++) acc[rg][ct] = (f32x4){0.f,0.f,0.f,0.f};

  const unsigned short* ardh = &Ahs[(wv*(16*RG) + mr)*40 + qd*8];
  const unsigned short* ardl = &Als[(wv*(16*RG) + mr)*40 + qd*8];
  const unsigned short* brdh = &Whs[mr*40 + qd*8];
  const unsigned short* brdl = &Wls[mr*40 + qd*8];

  const short8 z8 = {0,0,0,0,0,0,0,0};

  for (int kt = 0; kt < K; kt += 32){
    short8 ah[EA/8], al[EA/8];
    if (PS){
      #pragma unroll
      for (int h=0; h<EA/8; h++){
        ah[h] = *(const short8*)(Aph + kt + h*8);
        al[h] = *(const short8*)(Apl + kt + h*8);
      }
    } else {
      #pragma unroll
      for (int q=0; q<EA/4; q++){
        float4 f = *(const float4*)(Ap + kt + q*4);
        unsigned short ht[4], lt[4];
        split4(f, ht, lt);
        #pragma unroll
        for (int j=0;j<4;j++){
          ah[(q*4+j)/8][(q*4+j)&7] = (short)ht[j];
          al[(q*4+j)/8][(q*4+j)&7] = (short)lt[j];
        }
      }
    }
    short8 wh[EW/8], wl[EW/8];
    #pragma unroll
    for (int h=0; h<EW/8; h++){
      wh[h] = wok ? *(const short8*)(Whp + kt + h*8) : z8;
      wl[h] = wok ? *(const short8*)(Wlp + kt + h*8) : z8;
    }
    __syncthreads();
    #pragma unroll
    for (int h=0; h<EA/8; h++){
      *(short8*)&Ahs[arow*40 + aseg + h*8] = ah[h];
      *(short8*)&Als[arow*40 + aseg + h*8] = al[h];
    }
    #pragma unroll
    for (int h=0; h<EW/8; h++){
      *(short8*)&Whs[wrow*40 + wseg + h*8] = wh[h];
      *(short8*)&Wls[wrow*40 + wseg + h*8] = wl[h];
    }
    __syncthreads();
    #pragma unroll
    for (int rg=0; rg<RG; rg++){
      short8 af = *(const short8*)(ardh + rg*16*40);
      short8 alf= *(const short8*)(ardl + rg*16*40);
      #pragma unroll
      for (int ct=0; ct<CT; ct++){
        short8 bh = *(const short8*)(brdh + ct*16*40);
        short8 bl = *(const short8*)(brdl + ct*16*40);
        f32x4 t = acc[rg][ct];
        t = __builtin_amdgcn_mfma_f32_16x16x32_bf16(af, bh, t, 0,0,0);
        t = __builtin_amdgcn_mfma_f32_16x16x32_bf16(alf, bh, t, 0,0,0);
        t = __builtin_amdgcn_mfma_f32_16x16x32_bf16(af, bl, t, 0,0,0);
        acc[rg][ct] = t;
      }
    }
  }

  #pragma unroll
  for (int rg=0; rg<RG; rg++){
    #pragma unroll
    for (int ct=0; ct<CT; ct++){
      int colg = n0 + ct*16 + mr;
      if (colg >= N) continue;
      float bias_v = (EPI==0 || EPI==2) ? bias[colg] : 0.f;
      #pragma unroll
      for (int r=0;r<4;r++){
        int rowg = m0 + wv*(16*RG) + rg*16 + qd*4 + r;
        float v = acc[rg][ct][r];
        if (EPI == 0){ v += bias_v; }
        else if (EPI == 2){ v += bias_v; v = (v > 20.f) ? v : log1pf(expf(v)); }
        outp[(size_t)rowg*ldo + colg] = v;
      }
    }
  }
}

// 4-way partial-K reduce: out[i] = sum_z pp[z*n + i]
__global__ __launch_bounds__(256) void reduce4_kernel(
    const float* __restrict__ pp, float* __restrict__ out, int n)
{
  int i = (blockIdx.x*256 + threadIdx.x)*4;
  if (i >= n) return;
  float4 a = *(const float4*)(pp + i);
  float4 b = *(const float4*)(pp + n + i);
  float4 c = *(const float4*)(pp + 2*(size_t)n + i);
  float4 d = *(const float4*)(pp + 3*(size_t)n + i);
  float4 o;
  o.x = (a.x+b.x)+(c.x+d.x);
  o.y = (a.y+b.y)+(c.y+d.y);
  o.z = (a.z+b.z)+(c.z+d.z);
  o.w = (a.w+b.w)+(c.w+d.w);
  *(float4*)(out + i) = o;
}

// 2-way partial-K reduce + residual: out[i] = p0[i]+p1[i]+r[i]
__global__ __launch_bounds__(256) void reduce2r_kernel(
    const float* __restrict__ p0, const float* __restrict__ p1,
    const float* __restrict__ r, float* __restrict__ out, int n)
{
  int i = (blockIdx.x*256 + threadIdx.x)*4;
  if (i >= n) return;
  float4 a = *(const float4*)(p0 + i);
  float4 b = *(const float4*)(p1 + i);
  float4 c = *(const float4*)(r + i);
  float4 o;
  o.x = a.x+b.x+c.x; o.y = a.y+b.y+c.y; o.z = a.z+b.z+c.z; o.w = a.w+b.w+c.w;
  *(float4*)(out + i) = o;
}

// ---------------------------------------------------------------------------
// LayerNorm over D=1024 -> pre-split hi/lo bf16 (mamba branch)
// ---------------------------------------------------------------------------
__global__ __launch_bounds__(256) void ln_split_kernel(
    const float* __restrict__ x, const float* __restrict__ g, const float* __restrict__ b,
    unsigned short* __restrict__ hi, unsigned short* __restrict__ lo)
{
  int tok = blockIdx.x;
  int tid = threadIdx.x;
  const float* row = x + (size_t)tok * DMODEL;
  float v[4];
  float s = 0.f, sq = 0.f;
  #pragma unroll
  for (int j=0;j<4;j++){
    v[j] = row[j*256 + tid];
    s += v[j]; sq += v[j]*v[j];
  }
  #pragma unroll
  for (int o=1;o<64;o<<=1){ s += __shfl_xor(s,o,64); sq += __shfl_xor(sq,o,64); }
  __shared__ float ss[4], ssq[4];
  int wid = tid >> 6, lane = tid & 63;
  if (lane == 0){ ss[wid]=s; ssq[wid]=sq; }
  __syncthreads();
  s  = ss[0]+ss[1]+ss[2]+ss[3];
  sq = ssq[0]+ssq[1]+ssq[2]+ssq[3];
  float mu = s * (1.f/DMODEL);
  float var = sq * (1.f/DMODEL) - mu*mu;
  float rs = rsqrtf(var + 1e-5f);
  #pragma unroll
  for (int j=0;j<4;j++){
    int d = j*256 + tid;
    float o = (v[j]-mu)*rs*g[d] + b[d];
    unsigned short hu = f2bf(o);
    float hf = __uint_as_float((unsigned int)hu << 16);
    hi[(size_t)tok*DMODEL + d] = hu;
    lo[(size_t)tok*DMODEL + d] = f2bf(o - hf);
  }
}

// ---------------------------------------------------------------------------
// LayerNorm over D=1024 -> fp32 (router) + bf16 (moe_gemm1 A)
// ---------------------------------------------------------------------------
__global__ __launch_bounds__(256) void ln2_kernel(
    const float* __restrict__ x, const float* __restrict__ g, const float* __restrict__ b,
    float* __restrict__ out, unsigned short* __restrict__ outb)
{
  int tok = blockIdx.x;
  int tid = threadIdx.x;
  const float* row = x + (size_t)tok * DMODEL;
  float v[4];
  float s = 0.f, sq = 0.f;
  #pragma unroll
  for (int j=0;j<4;j++){
    v[j] = row[j*256 + tid];
    s += v[j]; sq += v[j]*v[j];
  }
  #pragma unroll
  for (int o=1;o<64;o<<=1){ s += __shfl_xor(s,o,64); sq += __shfl_xor(sq,o,64); }
  __shared__ float ss[4], ssq[4];
  int wid = tid >> 6, lane = tid & 63;
  if (lane == 0){ ss[wid]=s; ssq[wid]=sq; }
  __syncthreads();
  s  = ss[0]+ss[1]+ss[2]+ss[3];
  sq = ssq[0]+ssq[1]+ssq[2]+ssq[3];
  float mu = s * (1.f/DMODEL);
  float var = sq * (1.f/DMODEL) - mu*mu;
  float rs = rsqrtf(var + 1e-5f);
  #pragma unroll
  for (int j=0;j<4;j++){
    int d = j*256 + tid;
    float o = (v[j]-mu)*rs*g[d] + b[d];
    out[(size_t)tok*DMODEL + d] = o;
    outb[(size_t)tok*DMODEL + d] = f2bf(o);
  }
}

// ---------------------------------------------------------------------------
// Causal depthwise conv (KC=4) + SiLU.  xi = xz[:, 0:2048] (row stride 4096)
// ---------------------------------------------------------------------------
__global__ __launch_bounds__(256) void conv_kernel(
    const float* __restrict__ xz, const float* __restrict__ cw,
    const float* __restrict__ cb, float* __restrict__ xc)
{
  int i = blockIdx.x*256 + threadIdx.x;
  int tok = i >> 11;
  int ch  = i & 2047;
  int t   = tok & (TSEQ-1);
  int b   = tok >> 11;
  float acc = cb[ch];
  #pragma unroll
  for (int k=0;k<4;k++){
    int tt = t + k - 3;
    if (tt >= 0)
      acc = fmaf(cw[ch*4 + k], xz[(size_t)((b<<11)+tt)*4096 + ch], acc);
  }
  xc[i] = siluf(acc);
}

// ---------------------------------------------------------------------------
// Chunked parallel selective scan, lane-per-channel (verified round 2).
// ---------------------------------------------------------------------------
__global__ __launch_bounds__(256) void scan_partial(
    const float* __restrict__ xz, const float* __restrict__ xc,
    const float* __restrict__ proj, const float* __restrict__ A_log,
    float* __restrict__ P, float* __restrict__ Q)
{
  int tid = threadIdx.x;
  int ch  = blockIdx.x*256 + tid;
  int c   = blockIdx.y;
  int b   = blockIdx.z;
  float A[16];
  #pragma unroll
  for (int n=0;n<16;n++) A[n] = -expf(A_log[ch*NSTATE + n]);
  float h[16];
  #pragma unroll
  for (int n=0;n<16;n++) h[n] = 0.f;
  float sdt = 0.f;
  int tok0 = (b<<11) + c*CLEN;
  float dtv = xz[(size_t)tok0*4096 + ch];
  float xt  = xc[(size_t)tok0*2048 + ch];
  for (int i=0;i<CLEN;i++){
    int tn = tok0 + ((i+1 < CLEN) ? i+1 : i);
    float dtv_n = xz[(size_t)tn*4096 + ch];
    float xt_n  = xc[(size_t)tn*2048 + ch];
    const float4* pB = (const float4*)(proj + (size_t)(tok0+i)*96 + 64);
    float Bv[16];
    *(float4*)&Bv[0]  = pB[0];
    *(float4*)&Bv[4]  = pB[1];
    *(float4*)&Bv[8]  = pB[2];
    *(float4*)&Bv[12] = pB[3];
    float dxt = dtv*xt;
    sdt += dtv;
    #pragma unroll
    for (int n=0;n<16;n++){
      float dA = __expf(dtv*A[n]);
      h[n] = fmaf(dA, h[n], dxt*Bv[n]);
    }
    dtv = dtv_n; xt = xt_n;
  }
  size_t base = ((((size_t)(b*NCHUNK + c))<<11 | ch)<<4);
  #pragma unroll
  for (int n=0;n<16;n++){
    P[base+n] = __expf(A[n]*sdt);
    Q[base+n] = h[n];
  }
}

__global__ __launch_bounds__(256) void scan_combine(
    const float* __restrict__ Q, float* PH)
{
  int g = blockIdx.x*256 + threadIdx.x;
  int n = g & 15, ch = (g>>4) & 2047, b = g>>15;
  float hs = 0.f;
  for (int c=0;c<NCHUNK;c++){
    size_t idx = ((((size_t)(b*NCHUNK + c))<<11 | ch)<<4) | n;
    float pv = PH[idx];
    float qv = Q[idx];
    PH[idx] = hs;
    hs = fmaf(pv, hs, qv);
  }
}

__global__ __launch_bounds__(256) void scan_final(
    const float* __restrict__ xz, float* __restrict__ xc,
    const float* __restrict__ proj, const float* __restrict__ A_log,
    const float* __restrict__ Dskip, const float* __restrict__ Hs)
{
  int tid = threadIdx.x;
  int ch  = blockIdx.x*256 + tid;
  int c   = blockIdx.y;
  int b   = blockIdx.z;
  float A[16];
  #pragma unroll
  for (int n=0;n<16;n++) A[n] = -expf(A_log[ch*NSTATE + n]);
  float Dv = Dskip[ch];
  size_t base = ((((size_t)(b*NCHUNK + c))<<11 | ch)<<4);
  float h[16];
  #pragma unroll
  for (int n=0;n<16;n++) h[n] = Hs[base+n];
  int tok0 = (b<<11) + c*CLEN;
  float dtv = xz[(size_t)tok0*4096 + ch];
  float xt  = xc[(size_t)tok0*2048 + ch];
  float zv  = xz[(size_t)tok0*4096 + 2048 + ch];
  for (int i=0;i<CLEN;i++){
    int tn = tok0 + ((i+1 < CLEN) ? i+1 : i);
    float dtv_n = xz[(size_t)tn*4096 + ch];
    float xt_n  = xc[(size_t)tn*2048 + ch];
    float zv_n  = xz[(size_t)tn*4096 + 2048 + ch];
    const float4* pB = (const float4*)(proj + (size_t)(tok0+i)*96 + 64);
    float Bv[16], Cv[16];
    *(float4*)&Bv[0]  = pB[0];
    *(float4*)&Bv[4]  = pB[1];
    *(float4*)&Bv[8]  = pB[2];
    *(float4*)&Bv[12] = pB[3];
    *(float4*)&Cv[0]  = pB[4];
    *(float4*)&Cv[4]  = pB[5];
    *(float4*)&Cv[8]  = pB[6];
    *(float4*)&Cv[12] = pB[7];
    float dxt = dtv*xt;
    float y = xt*Dv;
    #pragma unroll
    for (int n=0;n<16;n++){
      float dA = __expf(dtv*A[n]);
      h[n] = fmaf(dA, h[n], dxt*Bv[n]);
      y = fmaf(h[n], Cv[n], y);
    }
    xc[(size_t)(tok0+i)*2048 + ch] = y * siluf(zv);
    dtv = dtv_n; xt = xt_n; zv = zv_n;
  }
}

// ---------------------------------------------------------------------------
// Router (kept precise: top-k decisions are tie-sensitive)
// ---------------------------------------------------------------------------
__global__ __launch_bounds__(256) void router_kernel(
    const float* __restrict__ hmoe, const float* __restrict__ rw,
    float* __restrict__ probs_out, int* __restrict__ cnt,
    int* __restrict__ tok_e0, int* __restrict__ tok_e1,
    float* __restrict__ tok_w0, float* __restrict__ tok_w1)
{
  int tok = blockIdx.x;
  int tid = threadIdx.x;
  int e = tid >> 5, l = tid & 31;
  float s = 0.f;
  const float* row = hmoe + (size_t)tok*DMODEL;
  const float* wr  = rw + (size_t)e*DMODEL;
  for (int d=l; d<DMODEL; d+=32) s = fmaf(row[d], wr[d], s);
  #pragma unroll
  for (int o=1;o<32;o<<=1) s += __shfl_xor(s,o,64);
  __shared__ float lg[8];
  if (l==0) lg[e]=s;
  __syncthreads();
  if (tid==0){
    float mx = lg[0];
    for (int k=1;k<8;k++) mx = fmaxf(mx, lg[k]);
    float pe[8]; float den=0.f;
    for (int k=0;k<8;k++){ pe[k]=expf(lg[k]-mx); den+=pe[k]; }
    float inv = 1.f/den;
    for (int k=0;k<8;k++) probs_out[tok*8+k] = pe[k]*inv;
    int i0=0;
    for (int k=1;k<8;k++) if (pe[k] > pe[i0]) i0=k;
    int i1 = (i0==0)?1:0;
    for (int k=0;k<8;k++) if (k!=i0 && pe[k] > pe[i1]) i1=k;
    float v0=pe[i0], v1=pe[i1], sw=v0+v1;
    tok_e0[tok]=i0; tok_e1[tok]=i1;
    tok_w0[tok]=v0/sw; tok_w1[tok]=v1/sw;
    atomicAdd(&cnt[i0],1); atomicAdd(&cnt[i1],1);
  }
}

__global__ void prefix_kernel(const int* cnt, int* off, int* fill){
  if (threadIdx.x==0){
    int s=0;
    for (int e=0;e<NEXP;e++){ off[e]=s; s+=cnt[e]; fill[e]=0; }
  }
}

__global__ __launch_bounds__(256) void fill_kernel(
    const int* tok_e0, const int* tok_e1, const float* tok_w0, const float* tok_w1,
    const int* off, int* fill, int* slot_tok, float* slot_w)
{
  int tok = blockIdx.x*256 + threadIdx.x;
  int e0=tok_e0[tok], e1=tok_e1[tok];
  int p0 = atomicAdd(&fill[e0],1); int s0 = off[e0]+p0;
  slot_tok[s0]=tok; slot_w[s0]=tok_w0[tok];
  int p1 = atomicAdd(&fill[e1],1); int s1 = off[e1]+p1;
  slot_tok[s1]=tok; slot_w[s1]=tok_w1[tok];
}

// ---------------------------------------------------------------------------
// MoE GEMM1 bf16 MFMA, BM=128 slots x BN=128: H1 = silu(hn_bf @ w1_bf^T + b1)
// ---------------------------------------------------------------------------
__global__ __launch_bounds__(256) void moe_gemm1(
    const unsigned short* __restrict__ hnb, const unsigned short* __restrict__ w1b,
    const float* __restrict__ b1,
    const int* __restrict__ cnt, const int* __restrict__ off,
    const int* __restrict__ slot_tok, unsigned short* __restrict__ H1)
{
  int e = blockIdx.z;
  int c = cnt[e];
  int r0 = blockIdx.y*128;
  if (r0 >= c) return;
  int base = off[e];
  int tid = threadIdx.x;
  __shared__ int toks[128];
  if (tid < 128) toks[tid] = (r0 + tid < c) ? slot_tok[base + r0 + tid] : -1;
  __shared__ __align__(16) unsigned short As[128*40];
  __shared__ __align__(16) unsigned short Ws[128*40];
  __syncthreads();

  const int n0   = blockIdx.x*128;
  const int srow = tid >> 1;
  const int sseg = (tid & 1) * 16;
  const int tok  = toks[srow];
  const bool aok = (tok >= 0);
  const unsigned short* Ap = hnb + (size_t)(aok ? tok : 0)*DMODEL + sseg;
  const unsigned short* Wp = w1b + (size_t)e*DFF*DMODEL + (size_t)(n0+srow)*DMODEL + sseg;

  const int lane = tid & 63;
  const int wv   = tid >> 6;
  const int qd   = lane >> 4;
  const int mr   = lane & 15;

  f32x4 acc[2][8];
  #pragma unroll
  for (int rg=0; rg<2; rg++)
    #pragma unroll
    for (int ct=0; ct<8; ct++) acc[rg][ct] = (f32x4){0.f,0.f,0.f,0.f};

  const unsigned short* ard = &As[(wv*32 + mr)*40 + qd*8];
  const unsigned short* brd = &Ws[mr*40 + qd*8];
  const short8 z8 = {0,0,0,0,0,0,0,0};

  for (int kt = 0; kt < DMODEL; kt += 32){
    short8 a0 = aok ? *(const short8*)(Ap + kt)     : z8;
    short8 a1 = aok ? *(const short8*)(Ap + kt + 8) : z8;
    short8 w0 = *(const short8*)(Wp + kt);
    short8 w1v= *(const short8*)(Wp + kt + 8);
    __syncthreads();
    *(short8*)&As[srow*40 + sseg]     = a0;
    *(short8*)&As[srow*40 + sseg + 8] = a1;
    *(short8*)&Ws[srow*40 + sseg]     = w0;
    *(short8*)&Ws[srow*40 + sseg + 8] = w1v;
    __syncthreads();
    #pragma unroll
    for (int rg=0; rg<2; rg++){
      short8 af = *(const short8*)(ard + rg*16*40);
      #pragma unroll
      for (int ct=0; ct<8; ct++){
        short8 bf = *(const short8*)(brd + ct*16*40);
        acc[rg][ct] = __builtin_amdgcn_mfma_f32_16x16x32_bf16(af, bf, acc[rg][ct], 0,0,0);
      }
    }
  }

  #pragma unroll
  for (int rg=0; rg<2; rg++){
    #pragma unroll
    for (int ct=0; ct<8; ct++){
      int colg = n0 + ct*16 + mr;
      float bias = b1[(size_t)e*DFF + colg];
      #pragma unroll
      for (int r=0;r<4;r++){
        int sl = wv*32 + rg*16 + qd*4 + r;
        if (toks[sl] < 0) continue;
        float v = acc[rg][ct][r] + bias;
        H1[(size_t)(base + r0 + sl)*DFF + colg] = f2bf(siluf(v));
      }
    }
  }
}

// ---------------------------------------------------------------------------
// MoE GEMM2 bf16 MFMA, BM=128 x BN=128: out += w_slot*(H1 @ w2_bf^T + b2)
// ---------------------------------------------------------------------------
__global__ __launch_bounds__(256) void moe_gemm2(
    const unsigned short* __restrict__ H1, const unsigned short* __restrict__ w2b,
    const float* __restrict__ b2,
    const int* __restrict__ cnt, const int* __restrict__ off,
    const int* __restrict__ slot_tok, const float* __restrict__ slot_w,
    float* __restrict__ hres)
{
  int e = blockIdx.z;
  int c = cnt[e];
  int r0 = blockIdx.y*128;
  if (r0 >= c) return;
  int base = off[e];
  int tid = threadIdx.x;
  __shared__ int toks[128];
  __shared__ float wts[128];
  if (tid < 128){
    int r = r0 + tid;
    toks[tid] = (r<c) ? slot_tok[base+r] : -1;
    wts[tid]  = (r<c) ? slot_w[base+r] : 0.f;
  }
  __shared__ __align__(16) unsigned short As[128*40];
  __shared__ __align__(16) unsigned short Ws[128*40];
  __syncthreads();

  const int n0   = blockIdx.x*128;
  const int srow = tid >> 1;
  const int sseg = (tid & 1) * 16;
  const bool aok = (toks[srow] >= 0);
  const unsigned short* Ap = H1 + (size_t)(base + r0 + (aok ? srow : 0))*DFF + sseg;
  const unsigned short* Wp = w2b + (size_t)e*DMODEL*DFF + (size_t)(n0+srow)*DFF + sseg;

  const int lane = tid & 63;
  const int wv   = tid >> 6;
  const int qd   = lane >> 4;
  const int mr   = lane & 15;

  f32x4 acc[2][8];
  #pragma unroll
  for (int rg=0; rg<2; rg++)
    #pragma unroll
    for (int ct=0; ct<8; ct++) acc[rg][ct] = (f32x4){0.f,0.f,0.f,0.f};

  const unsigned short* ard = &As[(wv*32 + mr)*40 + qd*8];
  const unsigned short* brd = &Ws[mr*40 + qd*8];
  const short8 z8 = {0,0,0,0,0,0,0,0};

  for (int kt = 0; kt < DFF; kt += 32){
    short8 a0 = aok ? *(const short8*)(Ap + kt)     : z8;
    short8 a1 = aok ? *(const short8*)(Ap + kt + 8) : z8;
    short8 w0 = *(const short8*)(Wp + kt);
    short8 w1v= *(const short8*)(Wp + kt + 8);
    __syncthreads();
    *(short8*)&As[srow*40 + sseg]     = a0;
    *(short8*)&As[srow*40 + sseg + 8] = a1;
    *(short8*)&Ws[srow*40 + sseg]     = w0;
    *(short8*)&Ws[srow*40 + sseg + 8] = w1v;
    __syncthreads();
    #pragma unroll
    for (int rg=0; rg<2; rg++){
      short8 af = *(const short8*)(ard + rg*16*40);
      #pragma unroll
      for (int ct=0; ct<8; ct++){
        short8 bf = *(const short8*)(brd + ct*16*40);
        acc[rg][ct] = __builtin_amdgcn_mfma_f32_16x16x32_bf16(af, bf, acc[rg][ct], 0,0,0);
      }
    }
  }

  #pragma unroll
  for (int rg=0; rg<2; rg++){
    #pragma unroll
    for (int ct=0; ct<8; ct++){
      int colg = n0 + ct*16 + mr;
      float bias = b2[(size_t)e*DMODEL + colg];
      #pragma unroll
      for (int r=0;r<4;r++){
        int sl = wv*32 + rg*16 + qd*4 + r;
        int t = toks[sl];
        if (t < 0) continue;
        float v = acc[rg][ct][r] + bias;
        atomicAdd(&hres[(size_t)t*DMODEL + colg], wts[sl]*v);
      }
    }
  }
}

// ---------------------------------------------------------------------------
extern "C" void kernel_launch(void* const* d_in, const int* in_sizes, int n_in,
                              void* d_out, int out_size, void* d_ws, size_t ws_size,
                              hipStream_t stream)
{
  const float* x         = (const float*)d_in[0];
  const float* ln_m_g    = (const float*)d_in[1];
  const float* ln_m_b    = (const float*)d_in[2];
  const float* ln_e_g    = (const float*)d_in[3];
  const float* ln_e_b    = (const float*)d_in[4];
  const float* in_proj_w = (const float*)d_in[5];
  const float* in_proj_b = (const float*)d_in[6];
  const float* conv_w    = (const float*)d_in[7];
  const float* conv_b    = (const float*)d_in[8];
  const float* x_proj_w  = (const float*)d_in[9];
  const float* dt_proj_w = (const float*)d_in[10];
  const float* dt_proj_b = (const float*)d_in[11];
  const float* A_log     = (const float*)d_in[12];
  const float* D_skip    = (const float*)d_in[13];
  const float* out_proj_w= (const float*)d_in[14];
  const float* router_w  = (const float*)d_in[15];
  const float* w1        = (const float*)d_in[16];
  const float* b1        = (const float*)d_in[17];
  const float* w2        = (const float*)d_in[18];
  const float* b2        = (const float*)d_in[19];

  // ws timeline:
  //   [0,64M)  xz (in_proj out; xi half rewritten by dt; scans consume)
  //            -> after scan_final: hn fp32 [0,16M); out_proj partials
  //               p0 [16M,32M) p1 [32M,48M) -> H1 bf16 [16M,48M);
  //               hn_bf [48M,56M)
  //   [64M,96M) Wi hi/lo (pre-conv) -> xc -> wmoe (w1_bf then w2_bf)
  //   [96M,97.5M) proj ; [97.5M,..) misc
  // d_out timeline:
  //   hn_hi [0,8M) hn_lo [8,16M) -> Wx/Wd [0,1.31M) + x_proj partials
  //   [2M,8.3M) -> P [0,8.39M) Q [8.39,16.78M) -> Wo [8.39M,16.39M)
  //   -> out_h [0,16M) (reduce2r; moe_gemm2 atomics) + probs [16.78M,..)
  char* ws = (char*)d_ws;
  float* xz   = (float*)(ws + 0);
  float* xc   = (float*)(ws + 67108864ull);
  float* proj = (float*)(ws + 100663296ull);
  char*  misc = ws + 102236160ull;
  float* hn   = (float*)(ws + 0);                               // post-scan
  float* pout = (float*)(ws + 16777216ull);                     // out_proj partials (2x16MB)
  unsigned short* H1    = (unsigned short*)(ws + 16777216ull);
  unsigned short* hn_bf = (unsigned short*)(ws + 50331648ull);
  unsigned short* wmoe  = (unsigned short*)(ws + 67108864ull);

  unsigned short* hn_hi = (unsigned short*)d_out;               // [0,8M)
  unsigned short* hn_lo = hn_hi + 4194304;                      // [8M,16M)
  float* Pbuf = (float*)d_out;                                  // 2M floats
  float* Qbuf = (float*)d_out + (2u<<20);                       // 2M floats
  float* ppx  = (float*)((char*)d_out + 2097152ull);            // x_proj partials 4x1.57MB

  unsigned short* Wi_hi = (unsigned short*)(ws + 67108864ull);
  unsigned short* Wi_lo = Wi_hi + 4194304;
  unsigned short* Wo_hi = (unsigned short*)Qbuf;                // d_out [8.39M,16.39M)
  unsigned short* Wo_lo = Wo_hi + 2097152;
  unsigned short* Wx_hi = (unsigned short*)d_out;
  unsigned short* Wx_lo = Wx_hi + 196608;
  unsigned short* Wd_hi = Wx_lo + 196608;
  unsigned short* Wd_lo = Wd_hi + 131072;

  int*   cnt      = (int*)(misc);
  int*   fill     = (int*)(misc + 64);
  int*   offp     = (int*)(misc + 128);
  int*   tok_e0   = (int*)(misc + 1024);
  int*   tok_e1   = (int*)(misc + 1024 + 16384);
  float* tok_w0   = (float*)(misc + 1024 + 32768);
  float* tok_w1   = (float*)(misc + 1024 + 49152);
  int*   slot_tok = (int*)(misc + 1024 + 65536);
  float* slot_w   = (float*)(misc + 1024 + 98304);
  float* out_h    = (float*)d_out;
  float* probs_out= (float*)d_out + 4194304;

  zero_kernel<<<1, 64, 0, stream>>>(cnt);

  // ---- Mamba branch ----
  split_kernel<<<4096, 256, 0, stream>>>(in_proj_w, Wi_hi, Wi_lo, 4194304);
  ln_split_kernel<<<NTOK, 256, 0, stream>>>(x, ln_m_g, ln_m_b, hn_hi, hn_lo);
  // in_proj: BM=128 x BN=256, grid 512 = 2 blocks/CU
  gemm_big<0,128,true,16,false><<<dim3(16, 32), 256, 0, stream>>>(
      nullptr, hn_hi, hn_lo, DMODEL, Wi_hi, Wi_lo, DMODEL, NTOK, 4096, DMODEL,
      in_proj_b, xz, 4096);
  split_kernel<<<192, 256, 0, stream>>>(x_proj_w, Wx_hi, Wx_lo, 196608);
  split_kernel<<<128, 256, 0, stream>>>(dt_proj_w, Wd_hi, Wd_lo, 131072);
  conv_kernel<<<NTOK*DINNER/256, 256, 0, stream>>>(xz, conv_w, conv_b, xc);
  // x_proj: split-K=4 (K=512/slice), BM=64 x BN=128, grid 256
  gemm_big<1,64,false,8,true><<<dim3(1, 64, 4), 256, 0, stream>>>(
      xc, nullptr, nullptr, DINNER, Wx_hi, Wx_lo, DINNER, NTOK, 96, 512,
      nullptr, ppx, 96);
  reduce4_kernel<<<384, 256, 0, stream>>>(ppx, proj, NTOK*96);
  gemm_big<2,128,false,8,false><<<dim3(16, 32), 256, 0, stream>>>(
      proj, nullptr, nullptr, 96, Wd_hi, Wd_lo, DTRANK, NTOK, DINNER, DTRANK,
      dt_proj_b, xz, 4096);
  scan_partial<<<dim3(DINNER/256, NCHUNK, 2), 256, 0, stream>>>(
      xz, xc, proj, A_log, Pbuf, Qbuf);
  scan_combine<<<256, 256, 0, stream>>>(Qbuf, Pbuf);
  scan_final<<<dim3(DINNER/256, NCHUNK, 2), 256, 0, stream>>>(
      xz, xc, proj, A_log, D_skip, Pbuf);
  // out_proj: split-K=2 (K=1024/slice), grid 512 = 2 blocks/CU; Wo in dead Qbuf
  split_kernel<<<2048, 256, 0, stream>>>(out_proj_w, Wo_hi, Wo_lo, 2097152);
  gemm_big<1,128,false,8,true><<<dim3(8, 32, 2), 256, 0, stream>>>(
      xc, nullptr, nullptr, DINNER, Wo_hi, Wo_lo, DINNER, NTOK, DMODEL, 1024,
      nullptr, pout, DMODEL);
  // h = p0 + p1 + x  -> final output region directly
  reduce2r_kernel<<<4096, 256, 0, stream>>>(pout, pout + 4194304, x, out_h,
                                            NTOK*DMODEL);

  // ---- MoE branch ----
  ln2_kernel<<<NTOK, 256, 0, stream>>>(out_h, ln_e_g, ln_e_b, hn, hn_bf);
  router_kernel<<<NTOK, 256, 0, stream>>>(hn, router_w, probs_out, cnt,
                                          tok_e0, tok_e1, tok_w0, tok_w1);
  prefix_kernel<<<1, 64, 0, stream>>>(cnt, offp, fill);
  fill_kernel<<<NTOK/256, 256, 0, stream>>>(tok_e0, tok_e1, tok_w0, tok_w1,
                                            offp, fill, slot_tok, slot_w);
  cvt_bf_kernel<<<8192, 256, 0, stream>>>(w1, wmoe, NEXP*DFF*DMODEL);
  moe_gemm1<<<dim3(DFF/128, 32, NEXP), 256, 0, stream>>>(
      hn_bf, wmoe, b1, cnt, offp, slot_tok, H1);
  cvt_bf_kernel<<<8192, 256, 0, stream>>>(w2, wmoe, NEXP*DMODEL*DFF);
  moe_gemm2<<<dim3(DMODEL/128, 32, NEXP), 256, 0, stream>>>(
      H1, wmoe, b2, cnt, offp, slot_tok, slot_w, out_h);
}

// Round 6
// 967.959 us; speedup vs baseline: 1.1316x; 1.1316x over previous
//
#include <hip/hip_runtime.h>
#include <hip/hip_bf16.h>
#include <math.h>

#define NTOK   4096   // B*T
#define TSEQ   2048
#define DMODEL 1024
#define DINNER 2048
#define NSTATE 16
#define DTRANK 64
#define NEXP   8
#define DFF    2048
#define NCHUNK 32
#define CLEN   64     // TSEQ / NCHUNK

typedef __attribute__((ext_vector_type(8))) short short8;
typedef __attribute__((ext_vector_type(4))) float f32x4;

__device__ __forceinline__ float fast_rcp(float x){ return __builtin_amdgcn_rcpf(x); }
__device__ __forceinline__ float siluf(float x){ return x * fast_rcp(1.f + __expf(-x)); }

// fp32 -> bf16 (round-to-nearest-even), as raw ushort
__device__ __forceinline__ unsigned short f2bf(float x){
  unsigned int u = __float_as_uint(x);
  unsigned int r = (u + 0x7FFFu + ((u >> 16) & 1u)) >> 16;
  return (unsigned short)r;
}

// split fp32 -> (hi, lo) bf16 pair: x ~= hi + lo, |err| <= 2^-18 |x|
__device__ __forceinline__ void split4(float4 a, unsigned short* hi, unsigned short* lo){
  float av[4] = {a.x, a.y, a.z, a.w};
  #pragma unroll
  for (int j=0;j<4;j++){
    unsigned short hu = f2bf(av[j]);
    float hf = __uint_as_float((unsigned int)hu << 16);
    hi[j] = hu;
    lo[j] = f2bf(av[j] - hf);
  }
}

// ---------------------------------------------------------------------------
__global__ void zero_kernel(int* __restrict__ p){ p[threadIdx.x] = 0; }

// ---------------------------------------------------------------------------
// Pre-split fp32 array into hi/lo bf16 arrays. n multiple of 1024.
// ---------------------------------------------------------------------------
__global__ __launch_bounds__(256) void split_kernel(
    const float* __restrict__ in, unsigned short* __restrict__ hi,
    unsigned short* __restrict__ lo, int n)
{
  int i = (blockIdx.x*256 + threadIdx.x)*4;
  if (i >= n) return;
  float4 v = *(const float4*)(in + i);
  unsigned short ht[4], lt[4];
  split4(v, ht, lt);
  uint2 hw, lw;
  hw.x = (unsigned)ht[0] | ((unsigned)ht[1]<<16);
  hw.y = (unsigned)ht[2] | ((unsigned)ht[3]<<16);
  lw.x = (unsigned)lt[0] | ((unsigned)lt[1]<<16);
  lw.y = (unsigned)lt[2] | ((unsigned)lt[3]<<16);
  *(uint2*)(hi+i) = hw;
  *(uint2*)(lo+i) = lw;
}

// fp32 -> bf16 convert (no split). n multiple of 2048.
__global__ __launch_bounds__(256) void cvt_bf_kernel(
    const float* __restrict__ in, unsigned short* __restrict__ out, int n)
{
  int i = (blockIdx.x*256 + threadIdx.x)*8;
  if (i >= n) return;
  float4 a = *(const float4*)(in+i);
  float4 b = *(const float4*)(in+i+4);
  short8 v;
  v[0]=(short)f2bf(a.x); v[1]=(short)f2bf(a.y); v[2]=(short)f2bf(a.z); v[3]=(short)f2bf(a.w);
  v[4]=(short)f2bf(b.x); v[5]=(short)f2bf(b.y); v[6]=(short)f2bf(b.z); v[7]=(short)f2bf(b.w);
  *(short8*)(out+i) = v;
}

// ---------------------------------------------------------------------------
// Split-bf16 MFMA GEMM: C[M,N] = A[M,K] @ W[N,K]^T (+epilogue), ~fp32 accuracy.
// W pre-split (Whi/Wlo). A either pre-split (PS=true) or fp32 (split in-kernel).
// Per product: ah*bh + al*bh + ah*bl (fp32 acc).
// Tile BM x (CT*16), BK=32, 256 threads / 4 waves; wave tile (16*RG) x (CT*16).
// NOTE: CT=8 is the proven sweet spot (84 VGPR / 40KB LDS / 2+ blocks/CU).
// CT=16 measured WORSE (144 VGPR, 60KB LDS -> 1 block/CU, 2x slower). Keep 8.
// SK=true: K is per-slice, blockIdx.z selects slice; out += z*M*ldo (partials).
// EPI: 0 = +bias | 1 = plain | 2 = +bias,softplus
// ---------------------------------------------------------------------------
template<int EPI, int BM, bool PS, int CT, bool SK>
__global__ __launch_bounds__(256) void gemm_big(
    const float* __restrict__ A,
    const unsigned short* __restrict__ Ahi, const unsigned short* __restrict__ Alo, int lda,
    const unsigned short* __restrict__ Whi, const unsigned short* __restrict__ Wlo, int ldw,
    int M, int N, int K,
    const float* __restrict__ bias,
    float* __restrict__ out, int ldo)
{
  constexpr int BN  = CT*16;
  constexpr int RG  = BM/64;       // 16-row groups per wave
  constexpr int TPR = 256/BM;      // threads per A row
  constexpr int EA  = 32/TPR;      // A elems per thread per ktile
  constexpr int TPW = 256/BN;      // threads per W row
  constexpr int EW  = 32/TPW;      // W elems per thread per ktile
  const int tid = threadIdx.x;
  const int m0 = blockIdx.y * BM;
  const int n0 = blockIdx.x * BN;
  const int koff = SK ? blockIdx.z * K : 0;
  float* outp = out + (SK ? (size_t)blockIdx.z * M * ldo : 0);

  __shared__ __align__(16) unsigned short Ahs[BM*40];
  __shared__ __align__(16) unsigned short Als[BM*40];
  __shared__ __align__(16) unsigned short Whs[BN*40];
  __shared__ __align__(16) unsigned short Wls[BN*40];

  const int arow = tid / TPR;
  const int aseg = (tid % TPR) * EA;
  const int wrow = tid / TPW;
  const int wseg = (tid % TPW) * EW;

  const float* Ap = PS ? nullptr : (A + (size_t)(m0 + arow)*lda + aseg + koff);
  const unsigned short* Aph = PS ? (Ahi + (size_t)(m0 + arow)*lda + aseg + koff) : nullptr;
  const unsigned short* Apl = PS ? (Alo + (size_t)(m0 + arow)*lda + aseg + koff) : nullptr;
  const bool wok = (n0 + wrow) < N;
  const unsigned short* Whp = Whi + (size_t)(n0 + wrow)*ldw + wseg + koff;
  const unsigned short* Wlp = Wlo + (size_t)(n0 + wrow)*ldw + wseg + koff;

  const int lane = tid & 63;
  const int wv   = tid >> 6;
  const int qd   = lane >> 4;
  const int mr   = lane & 15;

  f32x4 acc[RG][CT];
  #pragma unroll
  for (int rg=0; rg<RG; rg++)
    #pragma unroll
    for (int ct=0; ct<CT; ct++) acc[rg][ct] = (f32x4){0.f,0.f,0.f,0.f};

  const unsigned short* ardh = &Ahs[(wv*(16*RG) + mr)*40 + qd*8];
  const unsigned short* ardl = &Als[(wv*(16*RG) + mr)*40 + qd*8];
  const unsigned short* brdh = &Whs[mr*40 + qd*8];
  const unsigned short* brdl = &Wls[mr*40 + qd*8];

  const short8 z8 = {0,0,0,0,0,0,0,0};

  for (int kt = 0; kt < K; kt += 32){
    short8 ah[EA/8], al[EA/8];
    if (PS){
      #pragma unroll
      for (int h=0; h<EA/8; h++){
        ah[h] = *(const short8*)(Aph + kt + h*8);
        al[h] = *(const short8*)(Apl + kt + h*8);
      }
    } else {
      #pragma unroll
      for (int q=0; q<EA/4; q++){
        float4 f = *(const float4*)(Ap + kt + q*4);
        unsigned short ht[4], lt[4];
        split4(f, ht, lt);
        #pragma unroll
        for (int j=0;j<4;j++){
          ah[(q*4+j)/8][(q*4+j)&7] = (short)ht[j];
          al[(q*4+j)/8][(q*4+j)&7] = (short)lt[j];
        }
      }
    }
    short8 wh[EW/8], wl[EW/8];
    #pragma unroll
    for (int h=0; h<EW/8; h++){
      wh[h] = wok ? *(const short8*)(Whp + kt + h*8) : z8;
      wl[h] = wok ? *(const short8*)(Wlp + kt + h*8) : z8;
    }
    __syncthreads();
    #pragma unroll
    for (int h=0; h<EA/8; h++){
      *(short8*)&Ahs[arow*40 + aseg + h*8] = ah[h];
      *(short8*)&Als[arow*40 + aseg + h*8] = al[h];
    }
    #pragma unroll
    for (int h=0; h<EW/8; h++){
      *(short8*)&Whs[wrow*40 + wseg + h*8] = wh[h];
      *(short8*)&Wls[wrow*40 + wseg + h*8] = wl[h];
    }
    __syncthreads();
    #pragma unroll
    for (int rg=0; rg<RG; rg++){
      short8 af = *(const short8*)(ardh + rg*16*40);
      short8 alf= *(const short8*)(ardl + rg*16*40);
      #pragma unroll
      for (int ct=0; ct<CT; ct++){
        short8 bh = *(const short8*)(brdh + ct*16*40);
        short8 bl = *(const short8*)(brdl + ct*16*40);
        f32x4 t = acc[rg][ct];
        t = __builtin_amdgcn_mfma_f32_16x16x32_bf16(af, bh, t, 0,0,0);
        t = __builtin_amdgcn_mfma_f32_16x16x32_bf16(alf, bh, t, 0,0,0);
        t = __builtin_amdgcn_mfma_f32_16x16x32_bf16(af, bl, t, 0,0,0);
        acc[rg][ct] = t;
      }
    }
  }

  #pragma unroll
  for (int rg=0; rg<RG; rg++){
    #pragma unroll
    for (int ct=0; ct<CT; ct++){
      int colg = n0 + ct*16 + mr;
      if (colg >= N) continue;
      float bias_v = (EPI==0 || EPI==2) ? bias[colg] : 0.f;
      #pragma unroll
      for (int r=0;r<4;r++){
        int rowg = m0 + wv*(16*RG) + rg*16 + qd*4 + r;
        float v = acc[rg][ct][r];
        if (EPI == 0){ v += bias_v; }
        else if (EPI == 2){ v += bias_v; v = (v > 20.f) ? v : log1pf(expf(v)); }
        outp[(size_t)rowg*ldo + colg] = v;
      }
    }
  }
}

// 4-way partial-K reduce: out[i] = sum_z pp[z*n + i]
__global__ __launch_bounds__(256) void reduce4_kernel(
    const float* __restrict__ pp, float* __restrict__ out, int n)
{
  int i = (blockIdx.x*256 + threadIdx.x)*4;
  if (i >= n) return;
  float4 a = *(const float4*)(pp + i);
  float4 b = *(const float4*)(pp + n + i);
  float4 c = *(const float4*)(pp + 2*(size_t)n + i);
  float4 d = *(const float4*)(pp + 3*(size_t)n + i);
  float4 o;
  o.x = (a.x+b.x)+(c.x+d.x);
  o.y = (a.y+b.y)+(c.y+d.y);
  o.z = (a.z+b.z)+(c.z+d.z);
  o.w = (a.w+b.w)+(c.w+d.w);
  *(float4*)(out + i) = o;
}

// 2-way partial-K reduce + residual: out[i] = p0[i]+p1[i]+r[i]
__global__ __launch_bounds__(256) void reduce2r_kernel(
    const float* __restrict__ p0, const float* __restrict__ p1,
    const float* __restrict__ r, float* __restrict__ out, int n)
{
  int i = (blockIdx.x*256 + threadIdx.x)*4;
  if (i >= n) return;
  float4 a = *(const float4*)(p0 + i);
  float4 b = *(const float4*)(p1 + i);
  float4 c = *(const float4*)(r + i);
  float4 o;
  o.x = a.x+b.x+c.x; o.y = a.y+b.y+c.y; o.z = a.z+b.z+c.z; o.w = a.w+b.w+c.w;
  *(float4*)(out + i) = o;
}

// ---------------------------------------------------------------------------
// LayerNorm over D=1024 -> pre-split hi/lo bf16 (mamba branch)
// ---------------------------------------------------------------------------
__global__ __launch_bounds__(256) void ln_split_kernel(
    const float* __restrict__ x, const float* __restrict__ g, const float* __restrict__ b,
    unsigned short* __restrict__ hi, unsigned short* __restrict__ lo)
{
  int tok = blockIdx.x;
  int tid = threadIdx.x;
  const float* row = x + (size_t)tok * DMODEL;
  float v[4];
  float s = 0.f, sq = 0.f;
  #pragma unroll
  for (int j=0;j<4;j++){
    v[j] = row[j*256 + tid];
    s += v[j]; sq += v[j]*v[j];
  }
  #pragma unroll
  for (int o=1;o<64;o<<=1){ s += __shfl_xor(s,o,64); sq += __shfl_xor(sq,o,64); }
  __shared__ float ss[4], ssq[4];
  int wid = tid >> 6, lane = tid & 63;
  if (lane == 0){ ss[wid]=s; ssq[wid]=sq; }
  __syncthreads();
  s  = ss[0]+ss[1]+ss[2]+ss[3];
  sq = ssq[0]+ssq[1]+ssq[2]+ssq[3];
  float mu = s * (1.f/DMODEL);
  float var = sq * (1.f/DMODEL) - mu*mu;
  float rs = rsqrtf(var + 1e-5f);
  #pragma unroll
  for (int j=0;j<4;j++){
    int d = j*256 + tid;
    float o = (v[j]-mu)*rs*g[d] + b[d];
    unsigned short hu = f2bf(o);
    float hf = __uint_as_float((unsigned int)hu << 16);
    hi[(size_t)tok*DMODEL + d] = hu;
    lo[(size_t)tok*DMODEL + d] = f2bf(o - hf);
  }
}

// ---------------------------------------------------------------------------
// LayerNorm over D=1024 -> fp32 (router) + bf16 (moe_gemm1 A)
// ---------------------------------------------------------------------------
__global__ __launch_bounds__(256) void ln2_kernel(
    const float* __restrict__ x, const float* __restrict__ g, const float* __restrict__ b,
    float* __restrict__ out, unsigned short* __restrict__ outb)
{
  int tok = blockIdx.x;
  int tid = threadIdx.x;
  const float* row = x + (size_t)tok * DMODEL;
  float v[4];
  float s = 0.f, sq = 0.f;
  #pragma unroll
  for (int j=0;j<4;j++){
    v[j] = row[j*256 + tid];
    s += v[j]; sq += v[j]*v[j];
  }
  #pragma unroll
  for (int o=1;o<64;o<<=1){ s += __shfl_xor(s,o,64); sq += __shfl_xor(sq,o,64); }
  __shared__ float ss[4], ssq[4];
  int wid = tid >> 6, lane = tid & 63;
  if (lane == 0){ ss[wid]=s; ssq[wid]=sq; }
  __syncthreads();
  s  = ss[0]+ss[1]+ss[2]+ss[3];
  sq = ssq[0]+ssq[1]+ssq[2]+ssq[3];
  float mu = s * (1.f/DMODEL);
  float var = sq * (1.f/DMODEL) - mu*mu;
  float rs = rsqrtf(var + 1e-5f);
  #pragma unroll
  for (int j=0;j<4;j++){
    int d = j*256 + tid;
    float o = (v[j]-mu)*rs*g[d] + b[d];
    out[(size_t)tok*DMODEL + d] = o;
    outb[(size_t)tok*DMODEL + d] = f2bf(o);
  }
}

// ---------------------------------------------------------------------------
// Causal depthwise conv (KC=4) + SiLU.  xi = xz[:, 0:2048] (row stride 4096)
// ---------------------------------------------------------------------------
__global__ __launch_bounds__(256) void conv_kernel(
    const float* __restrict__ xz, const float* __restrict__ cw,
    const float* __restrict__ cb, float* __restrict__ xc)
{
  int i = blockIdx.x*256 + threadIdx.x;
  int tok = i >> 11;
  int ch  = i & 2047;
  int t   = tok & (TSEQ-1);
  int b   = tok >> 11;
  float acc = cb[ch];
  #pragma unroll
  for (int k=0;k<4;k++){
    int tt = t + k - 3;
    if (tt >= 0)
      acc = fmaf(cw[ch*4 + k], xz[(size_t)((b<<11)+tt)*4096 + ch], acc);
  }
  xc[i] = siluf(acc);
}

// ---------------------------------------------------------------------------
// Chunked parallel selective scan, lane-per-channel (verified round 2).
// ---------------------------------------------------------------------------
__global__ __launch_bounds__(256) void scan_partial(
    const float* __restrict__ xz, const float* __restrict__ xc,
    const float* __restrict__ proj, const float* __restrict__ A_log,
    float* __restrict__ P, float* __restrict__ Q)
{
  int tid = threadIdx.x;
  int ch  = blockIdx.x*256 + tid;
  int c   = blockIdx.y;
  int b   = blockIdx.z;
  float A[16];
  #pragma unroll
  for (int n=0;n<16;n++) A[n] = -expf(A_log[ch*NSTATE + n]);
  float h[16];
  #pragma unroll
  for (int n=0;n<16;n++) h[n] = 0.f;
  float sdt = 0.f;
  int tok0 = (b<<11) + c*CLEN;
  float dtv = xz[(size_t)tok0*4096 + ch];
  float xt  = xc[(size_t)tok0*2048 + ch];
  for (int i=0;i<CLEN;i++){
    int tn = tok0 + ((i+1 < CLEN) ? i+1 : i);
    float dtv_n = xz[(size_t)tn*4096 + ch];
    float xt_n  = xc[(size_t)tn*2048 + ch];
    const float4* pB = (const float4*)(proj + (size_t)(tok0+i)*96 + 64);
    float Bv[16];
    *(float4*)&Bv[0]  = pB[0];
    *(float4*)&Bv[4]  = pB[1];
    *(float4*)&Bv[8]  = pB[2];
    *(float4*)&Bv[12] = pB[3];
    float dxt = dtv*xt;
    sdt += dtv;
    #pragma unroll
    for (int n=0;n<16;n++){
      float dA = __expf(dtv*A[n]);
      h[n] = fmaf(dA, h[n], dxt*Bv[n]);
    }
    dtv = dtv_n; xt = xt_n;
  }
  size_t base = ((((size_t)(b*NCHUNK + c))<<11 | ch)<<4);
  #pragma unroll
  for (int n=0;n<16;n++){
    P[base+n] = __expf(A[n]*sdt);
    Q[base+n] = h[n];
  }
}

__global__ __launch_bounds__(256) void scan_combine(
    const float* __restrict__ Q, float* PH)
{
  int g = blockIdx.x*256 + threadIdx.x;
  int n = g & 15, ch = (g>>4) & 2047, b = g>>15;
  float hs = 0.f;
  for (int c=0;c<NCHUNK;c++){
    size_t idx = ((((size_t)(b*NCHUNK + c))<<11 | ch)<<4) | n;
    float pv = PH[idx];
    float qv = Q[idx];
    PH[idx] = hs;
    hs = fmaf(pv, hs, qv);
  }
}

__global__ __launch_bounds__(256) void scan_final(
    const float* __restrict__ xz, float* __restrict__ xc,
    const float* __restrict__ proj, const float* __restrict__ A_log,
    const float* __restrict__ Dskip, const float* __restrict__ Hs)
{
  int tid = threadIdx.x;
  int ch  = blockIdx.x*256 + tid;
  int c   = blockIdx.y;
  int b   = blockIdx.z;
  float A[16];
  #pragma unroll
  for (int n=0;n<16;n++) A[n] = -expf(A_log[ch*NSTATE + n]);
  float Dv = Dskip[ch];
  size_t base = ((((size_t)(b*NCHUNK + c))<<11 | ch)<<4);
  float h[16];
  #pragma unroll
  for (int n=0;n<16;n++) h[n] = Hs[base+n];
  int tok0 = (b<<11) + c*CLEN;
  float dtv = xz[(size_t)tok0*4096 + ch];
  float xt  = xc[(size_t)tok0*2048 + ch];
  float zv  = xz[(size_t)tok0*4096 + 2048 + ch];
  for (int i=0;i<CLEN;i++){
    int tn = tok0 + ((i+1 < CLEN) ? i+1 : i);
    float dtv_n = xz[(size_t)tn*4096 + ch];
    float xt_n  = xc[(size_t)tn*2048 + ch];
    float zv_n  = xz[(size_t)tn*4096 + 2048 + ch];
    const float4* pB = (const float4*)(proj + (size_t)(tok0+i)*96 + 64);
    float Bv[16], Cv[16];
    *(float4*)&Bv[0]  = pB[0];
    *(float4*)&Bv[4]  = pB[1];
    *(float4*)&Bv[8]  = pB[2];
    *(float4*)&Bv[12] = pB[3];
    *(float4*)&Cv[0]  = pB[4];
    *(float4*)&Cv[4]  = pB[5];
    *(float4*)&Cv[8]  = pB[6];
    *(float4*)&Cv[12] = pB[7];
    float dxt = dtv*xt;
    float y = xt*Dv;
    #pragma unroll
    for (int n=0;n<16;n++){
      float dA = __expf(dtv*A[n]);
      h[n] = fmaf(dA, h[n], dxt*Bv[n]);
      y = fmaf(h[n], Cv[n], y);
    }
    xc[(size_t)(tok0+i)*2048 + ch] = y * siluf(zv);
    dtv = dtv_n; xt = xt_n; zv = zv_n;
  }
}

// ---------------------------------------------------------------------------
// Router (kept precise: top-k decisions are tie-sensitive)
// ---------------------------------------------------------------------------
__global__ __launch_bounds__(256) void router_kernel(
    const float* __restrict__ hmoe, const float* __restrict__ rw,
    float* __restrict__ probs_out, int* __restrict__ cnt,
    int* __restrict__ tok_e0, int* __restrict__ tok_e1,
    float* __restrict__ tok_w0, float* __restrict__ tok_w1)
{
  int tok = blockIdx.x;
  int tid = threadIdx.x;
  int e = tid >> 5, l = tid & 31;
  float s = 0.f;
  const float* row = hmoe + (size_t)tok*DMODEL;
  const float* wr  = rw + (size_t)e*DMODEL;
  for (int d=l; d<DMODEL; d+=32) s = fmaf(row[d], wr[d], s);
  #pragma unroll
  for (int o=1;o<32;o<<=1) s += __shfl_xor(s,o,64);
  __shared__ float lg[8];
  if (l==0) lg[e]=s;
  __syncthreads();
  if (tid==0){
    float mx = lg[0];
    for (int k=1;k<8;k++) mx = fmaxf(mx, lg[k]);
    float pe[8]; float den=0.f;
    for (int k=0;k<8;k++){ pe[k]=expf(lg[k]-mx); den+=pe[k]; }
    float inv = 1.f/den;
    for (int k=0;k<8;k++) probs_out[tok*8+k] = pe[k]*inv;
    int i0=0;
    for (int k=1;k<8;k++) if (pe[k] > pe[i0]) i0=k;
    int i1 = (i0==0)?1:0;
    for (int k=0;k<8;k++) if (k!=i0 && pe[k] > pe[i1]) i1=k;
    float v0=pe[i0], v1=pe[i1], sw=v0+v1;
    tok_e0[tok]=i0; tok_e1[tok]=i1;
    tok_w0[tok]=v0/sw; tok_w1[tok]=v1/sw;
    atomicAdd(&cnt[i0],1); atomicAdd(&cnt[i1],1);
  }
}

__global__ void prefix_kernel(const int* cnt, int* off, int* fill){
  if (threadIdx.x==0){
    int s=0;
    for (int e=0;e<NEXP;e++){ off[e]=s; s+=cnt[e]; fill[e]=0; }
  }
}

__global__ __launch_bounds__(256) void fill_kernel(
    const int* tok_e0, const int* tok_e1, const float* tok_w0, const float* tok_w1,
    const int* off, int* fill, int* slot_tok, float* slot_w)
{
  int tok = blockIdx.x*256 + threadIdx.x;
  int e0=tok_e0[tok], e1=tok_e1[tok];
  int p0 = atomicAdd(&fill[e0],1); int s0 = off[e0]+p0;
  slot_tok[s0]=tok; slot_w[s0]=tok_w0[tok];
  int p1 = atomicAdd(&fill[e1],1); int s1 = off[e1]+p1;
  slot_tok[s1]=tok; slot_w[s1]=tok_w1[tok];
}

// ---------------------------------------------------------------------------
// MoE GEMM1 bf16 MFMA, BM=128 slots x BN=128: H1 = silu(hn_bf @ w1_bf^T + b1)
// ---------------------------------------------------------------------------
__global__ __launch_bounds__(256) void moe_gemm1(
    const unsigned short* __restrict__ hnb, const unsigned short* __restrict__ w1b,
    const float* __restrict__ b1,
    const int* __restrict__ cnt, const int* __restrict__ off,
    const int* __restrict__ slot_tok, unsigned short* __restrict__ H1)
{
  int e = blockIdx.z;
  int c = cnt[e];
  int r0 = blockIdx.y*128;
  if (r0 >= c) return;
  int base = off[e];
  int tid = threadIdx.x;
  __shared__ int toks[128];
  if (tid < 128) toks[tid] = (r0 + tid < c) ? slot_tok[base + r0 + tid] : -1;
  __shared__ __align__(16) unsigned short As[128*40];
  __shared__ __align__(16) unsigned short Ws[128*40];
  __syncthreads();

  const int n0   = blockIdx.x*128;
  const int srow = tid >> 1;
  const int sseg = (tid & 1) * 16;
  const int tok  = toks[srow];
  const bool aok = (tok >= 0);
  const unsigned short* Ap = hnb + (size_t)(aok ? tok : 0)*DMODEL + sseg;
  const unsigned short* Wp = w1b + (size_t)e*DFF*DMODEL + (size_t)(n0+srow)*DMODEL + sseg;

  const int lane = tid & 63;
  const int wv   = tid >> 6;
  const int qd   = lane >> 4;
  const int mr   = lane & 15;

  f32x4 acc[2][8];
  #pragma unroll
  for (int rg=0; rg<2; rg++)
    #pragma unroll
    for (int ct=0; ct<8; ct++) acc[rg][ct] = (f32x4){0.f,0.f,0.f,0.f};

  const unsigned short* ard = &As[(wv*32 + mr)*40 + qd*8];
  const unsigned short* brd = &Ws[mr*40 + qd*8];
  const short8 z8 = {0,0,0,0,0,0,0,0};

  for (int kt = 0; kt < DMODEL; kt += 32){
    short8 a0 = aok ? *(const short8*)(Ap + kt)     : z8;
    short8 a1 = aok ? *(const short8*)(Ap + kt + 8) : z8;
    short8 w0 = *(const short8*)(Wp + kt);
    short8 w1v= *(const short8*)(Wp + kt + 8);
    __syncthreads();
    *(short8*)&As[srow*40 + sseg]     = a0;
    *(short8*)&As[srow*40 + sseg + 8] = a1;
    *(short8*)&Ws[srow*40 + sseg]     = w0;
    *(short8*)&Ws[srow*40 + sseg + 8] = w1v;
    __syncthreads();
    #pragma unroll
    for (int rg=0; rg<2; rg++){
      short8 af = *(const short8*)(ard + rg*16*40);
      #pragma unroll
      for (int ct=0; ct<8; ct++){
        short8 bf = *(const short8*)(brd + ct*16*40);
        acc[rg][ct] = __builtin_amdgcn_mfma_f32_16x16x32_bf16(af, bf, acc[rg][ct], 0,0,0);
      }
    }
  }

  #pragma unroll
  for (int rg=0; rg<2; rg++){
    #pragma unroll
    for (int ct=0; ct<8; ct++){
      int colg = n0 + ct*16 + mr;
      float bias = b1[(size_t)e*DFF + colg];
      #pragma unroll
      for (int r=0;r<4;r++){
        int sl = wv*32 + rg*16 + qd*4 + r;
        if (toks[sl] < 0) continue;
        float v = acc[rg][ct][r] + bias;
        H1[(size_t)(base + r0 + sl)*DFF + colg] = f2bf(siluf(v));
      }
    }
  }
}

// ---------------------------------------------------------------------------
// MoE GEMM2 bf16 MFMA, BM=128 x BN=128: out += w_slot*(H1 @ w2_bf^T + b2)
// ---------------------------------------------------------------------------
__global__ __launch_bounds__(256) void moe_gemm2(
    const unsigned short* __restrict__ H1, const unsigned short* __restrict__ w2b,
    const float* __restrict__ b2,
    const int* __restrict__ cnt, const int* __restrict__ off,
    const int* __restrict__ slot_tok, const float* __restrict__ slot_w,
    float* __restrict__ hres)
{
  int e = blockIdx.z;
  int c = cnt[e];
  int r0 = blockIdx.y*128;
  if (r0 >= c) return;
  int base = off[e];
  int tid = threadIdx.x;
  __shared__ int toks[128];
  __shared__ float wts[128];
  if (tid < 128){
    int r = r0 + tid;
    toks[tid] = (r<c) ? slot_tok[base+r] : -1;
    wts[tid]  = (r<c) ? slot_w[base+r] : 0.f;
  }
  __shared__ __align__(16) unsigned short As[128*40];
  __shared__ __align__(16) unsigned short Ws[128*40];
  __syncthreads();

  const int n0   = blockIdx.x*128;
  const int srow = tid >> 1;
  const int sseg = (tid & 1) * 16;
  const bool aok = (toks[srow] >= 0);
  const unsigned short* Ap = H1 + (size_t)(base + r0 + (aok ? srow : 0))*DFF + sseg;
  const unsigned short* Wp = w2b + (size_t)e*DMODEL*DFF + (size_t)(n0+srow)*DFF + sseg;

  const int lane = tid & 63;
  const int wv   = tid >> 6;
  const int qd   = lane >> 4;
  const int mr   = lane & 15;

  f32x4 acc[2][8];
  #pragma unroll
  for (int rg=0; rg<2; rg++)
    #pragma unroll
    for (int ct=0; ct<8; ct++) acc[rg][ct] = (f32x4){0.f,0.f,0.f,0.f};

  const unsigned short* ard = &As[(wv*32 + mr)*40 + qd*8];
  const unsigned short* brd = &Ws[mr*40 + qd*8];
  const short8 z8 = {0,0,0,0,0,0,0,0};

  for (int kt = 0; kt < DFF; kt += 32){
    short8 a0 = aok ? *(const short8*)(Ap + kt)     : z8;
    short8 a1 = aok ? *(const short8*)(Ap + kt + 8) : z8;
    short8 w0 = *(const short8*)(Wp + kt);
    short8 w1v= *(const short8*)(Wp + kt + 8);
    __syncthreads();
    *(short8*)&As[srow*40 + sseg]     = a0;
    *(short8*)&As[srow*40 + sseg + 8] = a1;
    *(short8*)&Ws[srow*40 + sseg]     = w0;
    *(short8*)&Ws[srow*40 + sseg + 8] = w1v;
    __syncthreads();
    #pragma unroll
    for (int rg=0; rg<2; rg++){
      short8 af = *(const short8*)(ard + rg*16*40);
      #pragma unroll
      for (int ct=0; ct<8; ct++){
        short8 bf = *(const short8*)(brd + ct*16*40);
        acc[rg][ct] = __builtin_amdgcn_mfma_f32_16x16x32_bf16(af, bf, acc[rg][ct], 0,0,0);
      }
    }
  }

  #pragma unroll
  for (int rg=0; rg<2; rg++){
    #pragma unroll
    for (int ct=0; ct<8; ct++){
      int colg = n0 + ct*16 + mr;
      float bias = b2[(size_t)e*DMODEL + colg];
      #pragma unroll
      for (int r=0;r<4;r++){
        int sl = wv*32 + rg*16 + qd*4 + r;
        int t = toks[sl];
        if (t < 0) continue;
        float v = acc[rg][ct][r] + bias;
        atomicAdd(&hres[(size_t)t*DMODEL + colg], wts[sl]*v);
      }
    }
  }
}

// ---------------------------------------------------------------------------
extern "C" void kernel_launch(void* const* d_in, const int* in_sizes, int n_in,
                              void* d_out, int out_size, void* d_ws, size_t ws_size,
                              hipStream_t stream)
{
  const float* x         = (const float*)d_in[0];
  const float* ln_m_g    = (const float*)d_in[1];
  const float* ln_m_b    = (const float*)d_in[2];
  const float* ln_e_g    = (const float*)d_in[3];
  const float* ln_e_b    = (const float*)d_in[4];
  const float* in_proj_w = (const float*)d_in[5];
  const float* in_proj_b = (const float*)d_in[6];
  const float* conv_w    = (const float*)d_in[7];
  const float* conv_b    = (const float*)d_in[8];
  const float* x_proj_w  = (const float*)d_in[9];
  const float* dt_proj_w = (const float*)d_in[10];
  const float* dt_proj_b = (const float*)d_in[11];
  const float* A_log     = (const float*)d_in[12];
  const float* D_skip    = (const float*)d_in[13];
  const float* out_proj_w= (const float*)d_in[14];
  const float* router_w  = (const float*)d_in[15];
  const float* w1        = (const float*)d_in[16];
  const float* b1        = (const float*)d_in[17];
  const float* w2        = (const float*)d_in[18];
  const float* b2        = (const float*)d_in[19];

  // ws timeline:
  //   [0,64M)  xz (in_proj out; xi half rewritten by dt; scans consume)
  //            -> after scan_final: hn fp32 [0,16M); out_proj partials
  //               p0 [16M,32M) p1 [32M,48M) -> H1 bf16 [16M,48M);
  //               hn_bf [48M,56M)
  //   [64M,96M) Wi hi/lo (pre-conv) -> xc -> wmoe (w1_bf then w2_bf)
  //   [96M,97.5M) proj ; [97.5M,..) misc
  // d_out timeline:
  //   hn_hi [0,8M) hn_lo [8,16M) -> Wx/Wd [0,1.31M) + x_proj partials
  //   [2M,8.3M) -> P [0,8.39M) Q [8.39,16.78M) -> Wo [8.39M,16.39M)
  //   -> out_h [0,16M) (reduce2r; moe_gemm2 atomics) + probs [16.78M,..)
  char* ws = (char*)d_ws;
  float* xz   = (float*)(ws + 0);
  float* xc   = (float*)(ws + 67108864ull);
  float* proj = (float*)(ws + 100663296ull);
  char*  misc = ws + 102236160ull;
  float* hn   = (float*)(ws + 0);                               // post-scan
  float* pout = (float*)(ws + 16777216ull);                     // out_proj partials (2x16MB)
  unsigned short* H1    = (unsigned short*)(ws + 16777216ull);
  unsigned short* hn_bf = (unsigned short*)(ws + 50331648ull);
  unsigned short* wmoe  = (unsigned short*)(ws + 67108864ull);

  unsigned short* hn_hi = (unsigned short*)d_out;               // [0,8M)
  unsigned short* hn_lo = hn_hi + 4194304;                      // [8M,16M)
  float* Pbuf = (float*)d_out;                                  // 2M floats
  float* Qbuf = (float*)d_out + (2u<<20);                       // 2M floats
  float* ppx  = (float*)((char*)d_out + 2097152ull);            // x_proj partials 4x1.57MB

  unsigned short* Wi_hi = (unsigned short*)(ws + 67108864ull);
  unsigned short* Wi_lo = Wi_hi + 4194304;
  unsigned short* Wo_hi = (unsigned short*)Qbuf;                // d_out [8.39M,16.39M)
  unsigned short* Wo_lo = Wo_hi + 2097152;
  unsigned short* Wx_hi = (unsigned short*)d_out;
  unsigned short* Wx_lo = Wx_hi + 196608;
  unsigned short* Wd_hi = Wx_lo + 196608;
  unsigned short* Wd_lo = Wd_hi + 131072;

  int*   cnt      = (int*)(misc);
  int*   fill     = (int*)(misc + 64);
  int*   offp     = (int*)(misc + 128);
  int*   tok_e0   = (int*)(misc + 1024);
  int*   tok_e1   = (int*)(misc + 1024 + 16384);
  float* tok_w0   = (float*)(misc + 1024 + 32768);
  float* tok_w1   = (float*)(misc + 1024 + 49152);
  int*   slot_tok = (int*)(misc + 1024 + 65536);
  float* slot_w   = (float*)(misc + 1024 + 98304);
  float* out_h    = (float*)d_out;
  float* probs_out= (float*)d_out + 4194304;

  zero_kernel<<<1, 64, 0, stream>>>(cnt);

  // ---- Mamba branch ----
  split_kernel<<<4096, 256, 0, stream>>>(in_proj_w, Wi_hi, Wi_lo, 4194304);
  ln_split_kernel<<<NTOK, 256, 0, stream>>>(x, ln_m_g, ln_m_b, hn_hi, hn_lo);
  // in_proj: BM=128 x BN=128 (CT=8, proven config), grid 1024 blocks
  gemm_big<0,128,true,8,false><<<dim3(32, 32), 256, 0, stream>>>(
      nullptr, hn_hi, hn_lo, DMODEL, Wi_hi, Wi_lo, DMODEL, NTOK, 4096, DMODEL,
      in_proj_b, xz, 4096);
  split_kernel<<<192, 256, 0, stream>>>(x_proj_w, Wx_hi, Wx_lo, 196608);
  split_kernel<<<128, 256, 0, stream>>>(dt_proj_w, Wd_hi, Wd_lo, 131072);
  conv_kernel<<<NTOK*DINNER/256, 256, 0, stream>>>(xz, conv_w, conv_b, xc);
  // x_proj: split-K=4 (K=512/slice), BM=64 x BN=128, grid 256
  gemm_big<1,64,false,8,true><<<dim3(1, 64, 4), 256, 0, stream>>>(
      xc, nullptr, nullptr, DINNER, Wx_hi, Wx_lo, DINNER, NTOK, 96, 512,
      nullptr, ppx, 96);
  reduce4_kernel<<<384, 256, 0, stream>>>(ppx, proj, NTOK*96);
  gemm_big<2,128,false,8,false><<<dim3(16, 32), 256, 0, stream>>>(
      proj, nullptr, nullptr, 96, Wd_hi, Wd_lo, DTRANK, NTOK, DINNER, DTRANK,
      dt_proj_b, xz, 4096);
  scan_partial<<<dim3(DINNER/256, NCHUNK, 2), 256, 0, stream>>>(
      xz, xc, proj, A_log, Pbuf, Qbuf);
  scan_combine<<<256, 256, 0, stream>>>(Qbuf, Pbuf);
  scan_final<<<dim3(DINNER/256, NCHUNK, 2), 256, 0, stream>>>(
      xz, xc, proj, A_log, D_skip, Pbuf);
  // out_proj: split-K=2 (K=1024/slice), grid 512 = 2 blocks/CU; Wo in dead Qbuf
  split_kernel<<<2048, 256, 0, stream>>>(out_proj_w, Wo_hi, Wo_lo, 2097152);
  gemm_big<1,128,false,8,true><<<dim3(8, 32, 2), 256, 0, stream>>>(
      xc, nullptr, nullptr, DINNER, Wo_hi, Wo_lo, DINNER, NTOK, DMODEL, 1024,
      nullptr, pout, DMODEL);
  // h = p0 + p1 + x  -> final output region directly
  reduce2r_kernel<<<4096, 256, 0, stream>>>(pout, pout + 4194304, x, out_h,
                                            NTOK*DMODEL);

  // ---- MoE branch ----
  ln2_kernel<<<NTOK, 256, 0, stream>>>(out_h, ln_e_g, ln_e_b, hn, hn_bf);
  router_kernel<<<NTOK, 256, 0, stream>>>(hn, router_w, probs_out, cnt,
                                          tok_e0, tok_e1, tok_w0, tok_w1);
  prefix_kernel<<<1, 64, 0, stream>>>(cnt, offp, fill);
  fill_kernel<<<NTOK/256, 256, 0, stream>>>(tok_e0, tok_e1, tok_w0, tok_w1,
                                            offp, fill, slot_tok, slot_w);
  cvt_bf_kernel<<<8192, 256, 0, stream>>>(w1, wmoe, NEXP*DFF*DMODEL);
  moe_gemm1<<<dim3(DFF/128, 32, NEXP), 256, 0, stream>>>(
      hn_bf, wmoe, b1, cnt, offp, slot_tok, H1);
  cvt_bf_kernel<<<8192, 256, 0, stream>>>(w2, wmoe, NEXP*DMODEL*DFF);
  moe_gemm2<<<dim3(DMODEL/128, 32, NEXP), 256, 0, stream>>>(
      H1, wmoe, b2, cnt, offp, slot_tok, slot_w, out_h);
}

// Round 7
// 936.193 us; speedup vs baseline: 1.1700x; 1.0339x over previous
//
#include <hip/hip_runtime.h>
#include <hip/hip_bf16.h>
#include <math.h>

#define NTOK   4096   // B*T
#define TSEQ   2048
#define DMODEL 1024
#define DINNER 2048
#define NSTATE 16
#define DTRANK 64
#define NEXP   8
#define DFF    2048
#define NCHUNK 32
#define CLEN   64     // TSEQ / NCHUNK

typedef __attribute__((ext_vector_type(8))) short short8;
typedef __attribute__((ext_vector_type(4))) float f32x4;

__device__ __forceinline__ float fast_rcp(float x){ return __builtin_amdgcn_rcpf(x); }
__device__ __forceinline__ float siluf(float x){ return x * fast_rcp(1.f + __expf(-x)); }

// fp32 -> bf16 (round-to-nearest-even), as raw ushort
__device__ __forceinline__ unsigned short f2bf(float x){
  unsigned int u = __float_as_uint(x);
  unsigned int r = (u + 0x7FFFu + ((u >> 16) & 1u)) >> 16;
  return (unsigned short)r;
}

// split fp32 -> (hi, lo) bf16 pair: x ~= hi + lo, |err| <= 2^-18 |x|
__device__ __forceinline__ void split4(float4 a, unsigned short* hi, unsigned short* lo){
  float av[4] = {a.x, a.y, a.z, a.w};
  #pragma unroll
  for (int j=0;j<4;j++){
    unsigned short hu = f2bf(av[j]);
    float hf = __uint_as_float((unsigned int)hu << 16);
    hi[j] = hu;
    lo[j] = f2bf(av[j] - hf);
  }
}

// ---------------------------------------------------------------------------
__global__ void zero_kernel(int* __restrict__ p){ p[threadIdx.x] = 0; }

// ---------------------------------------------------------------------------
// Pre-split fp32 array into hi/lo bf16 arrays. n multiple of 1024.
// ---------------------------------------------------------------------------
__global__ __launch_bounds__(256) void split_kernel(
    const float* __restrict__ in, unsigned short* __restrict__ hi,
    unsigned short* __restrict__ lo, int n)
{
  int i = (blockIdx.x*256 + threadIdx.x)*4;
  if (i >= n) return;
  float4 v = *(const float4*)(in + i);
  unsigned short ht[4], lt[4];
  split4(v, ht, lt);
  uint2 hw, lw;
  hw.x = (unsigned)ht[0] | ((unsigned)ht[1]<<16);
  hw.y = (unsigned)ht[2] | ((unsigned)ht[3]<<16);
  lw.x = (unsigned)lt[0] | ((unsigned)lt[1]<<16);
  lw.y = (unsigned)lt[2] | ((unsigned)lt[3]<<16);
  *(uint2*)(hi+i) = hw;
  *(uint2*)(lo+i) = lw;
}

// fp32 -> bf16 convert (no split). n multiple of 2048.
__global__ __launch_bounds__(256) void cvt_bf_kernel(
    const float* __restrict__ in, unsigned short* __restrict__ out, int n)
{
  int i = (blockIdx.x*256 + threadIdx.x)*8;
  if (i >= n) return;
  float4 a = *(const float4*)(in+i);
  float4 b = *(const float4*)(in+i+4);
  short8 v;
  v[0]=(short)f2bf(a.x); v[1]=(short)f2bf(a.y); v[2]=(short)f2bf(a.z); v[3]=(short)f2bf(a.w);
  v[4]=(short)f2bf(b.x); v[5]=(short)f2bf(b.y); v[6]=(short)f2bf(b.z); v[7]=(short)f2bf(b.w);
  *(short8*)(out+i) = v;
}

// ---------------------------------------------------------------------------
// Split-bf16 MFMA GEMM: C[M,N] = A[M,K] @ W[N,K]^T (+epilogue), ~fp32 accuracy.
// W pre-split (Whi/Wlo). A either pre-split (PS=true) or fp32 (split in-kernel).
// Per product: ah*bh + al*bh + ah*bl (fp32 acc).
// Tile BM x (CT*16), BK=32, 256 threads / 4 waves; wave tile (16*RG) x (CT*16).
// CT=8 proven (CT=16 halves occupancy: measured 2x WORSE in round 5).
// LDS DOUBLE-BUFFERED, one barrier per K-iter; next-tile globals issued
// before the MFMA phase so HBM latency hides under compute (T3/T14 recipe).
// SK=true: K is per-slice, blockIdx.z selects slice; out += z*M*ldo (partials).
// EPI: 0 = +bias | 1 = plain | 2 = +bias,softplus
// ---------------------------------------------------------------------------
template<int EPI, int BM, bool PS, int CT, bool SK>
__global__ __launch_bounds__(256) void gemm_big(
    const float* __restrict__ A,
    const unsigned short* __restrict__ Ahi, const unsigned short* __restrict__ Alo, int lda,
    const unsigned short* __restrict__ Whi, const unsigned short* __restrict__ Wlo, int ldw,
    int M, int N, int K,
    const float* __restrict__ bias,
    float* __restrict__ out, int ldo)
{
  constexpr int BN  = CT*16;
  constexpr int RG  = BM/64;       // 16-row groups per wave
  constexpr int TPR = 256/BM;      // threads per A row
  constexpr int EA  = 32/TPR;      // A elems per thread per ktile
  constexpr int TPW = 256/BN;      // threads per W row
  constexpr int EW  = 32/TPW;      // W elems per thread per ktile
  constexpr int AH  = BM*40;       // one A buffer (shorts)
  constexpr int WH  = BN*40;       // one W buffer (shorts)
  const int tid = threadIdx.x;
  const int m0 = blockIdx.y * BM;
  const int n0 = blockIdx.x * BN;
  const int koff = SK ? blockIdx.z * K : 0;
  float* outp = out + (SK ? (size_t)blockIdx.z * M * ldo : 0);

  __shared__ __align__(16) unsigned short Ahs[2*AH];
  __shared__ __align__(16) unsigned short Als[2*AH];
  __shared__ __align__(16) unsigned short Whs[2*WH];
  __shared__ __align__(16) unsigned short Wls[2*WH];

  const int arow = tid / TPR;
  const int aseg = (tid % TPR) * EA;
  const int wrow = tid / TPW;
  const int wseg = (tid % TPW) * EW;

  const float* Ap = PS ? nullptr : (A + (size_t)(m0 + arow)*lda + aseg + koff);
  const unsigned short* Aph = PS ? (Ahi + (size_t)(m0 + arow)*lda + aseg + koff) : nullptr;
  const unsigned short* Apl = PS ? (Alo + (size_t)(m0 + arow)*lda + aseg + koff) : nullptr;
  const bool wok = (n0 + wrow) < N;
  const unsigned short* Whp = Whi + (size_t)(n0 + wrow)*ldw + wseg + koff;
  const unsigned short* Wlp = Wlo + (size_t)(n0 + wrow)*ldw + wseg + koff;

  const int lane = tid & 63;
  const int wv   = tid >> 6;
  const int qd   = lane >> 4;
  const int mr   = lane & 15;

  f32x4 acc[RG][CT];
  #pragma unroll
  for (int rg=0; rg<RG; rg++)
    #pragma unroll
    for (int ct=0; ct<CT; ct++) acc[rg][ct] = (f32x4){0.f,0.f,0.f,0.f};

  const int ard_o = (wv*(16*RG) + mr)*40 + qd*8;
  const int brd_o = mr*40 + qd*8;
  const short8 z8 = {0,0,0,0,0,0,0,0};

  short8 ah[EA/8], al[EA/8], wh[EW/8], wl[EW/8];

  // --- load tile kt into regs ---
  auto load_tile = [&](int kt){
    if (PS){
      #pragma unroll
      for (int h=0; h<EA/8; h++){
        ah[h] = *(const short8*)(Aph + kt + h*8);
        al[h] = *(const short8*)(Apl + kt + h*8);
      }
    } else {
      #pragma unroll
      for (int q=0; q<EA/4; q++){
        float4 f = *(const float4*)(Ap + kt + q*4);
        unsigned short ht[4], lt[4];
        split4(f, ht, lt);
        #pragma unroll
        for (int j=0;j<4;j++){
          ah[(q*4+j)/8][(q*4+j)&7] = (short)ht[j];
          al[(q*4+j)/8][(q*4+j)&7] = (short)lt[j];
        }
      }
    }
    #pragma unroll
    for (int h=0; h<EW/8; h++){
      wh[h] = wok ? *(const short8*)(Whp + kt + h*8) : z8;
      wl[h] = wok ? *(const short8*)(Wlp + kt + h*8) : z8;
    }
  };
  // --- store regs into LDS buffer b ---
  auto store_tile = [&](int b){
    #pragma unroll
    for (int h=0; h<EA/8; h++){
      *(short8*)&Ahs[b*AH + arow*40 + aseg + h*8] = ah[h];
      *(short8*)&Als[b*AH + arow*40 + aseg + h*8] = al[h];
    }
    #pragma unroll
    for (int h=0; h<EW/8; h++){
      *(short8*)&Whs[b*WH + wrow*40 + wseg + h*8] = wh[h];
      *(short8*)&Wls[b*WH + wrow*40 + wseg + h*8] = wl[h];
    }
  };

  // prologue: tile 0 -> buf 0
  load_tile(0);
  store_tile(0);
  __syncthreads();

  int cur = 0;
  for (int kt = 0; kt < K; kt += 32){
    const bool hn = (kt + 32 < K);
    if (hn) load_tile(kt + 32);          // issue next-tile globals early
    // MFMA phase from buf[cur]
    #pragma unroll
    for (int rg=0; rg<RG; rg++){
      short8 af = *(const short8*)&Ahs[cur*AH + ard_o + rg*16*40];
      short8 alf= *(const short8*)&Als[cur*AH + ard_o + rg*16*40];
      #pragma unroll
      for (int ct=0; ct<CT; ct++){
        short8 bh = *(const short8*)&Whs[cur*WH + brd_o + ct*16*40];
        short8 bl = *(const short8*)&Wls[cur*WH + brd_o + ct*16*40];
        f32x4 t = acc[rg][ct];
        t = __builtin_amdgcn_mfma_f32_16x16x32_bf16(af, bh, t, 0,0,0);
        t = __builtin_amdgcn_mfma_f32_16x16x32_bf16(alf, bh, t, 0,0,0);
        t = __builtin_amdgcn_mfma_f32_16x16x32_bf16(af, bl, t, 0,0,0);
        acc[rg][ct] = t;
      }
    }
    if (hn) store_tile(cur ^ 1);         // write next tile to other buffer
    __syncthreads();                     // single barrier per iteration
    cur ^= 1;
  }

  #pragma unroll
  for (int rg=0; rg<RG; rg++){
    #pragma unroll
    for (int ct=0; ct<CT; ct++){
      int colg = n0 + ct*16 + mr;
      if (colg >= N) continue;
      float bias_v = (EPI==0 || EPI==2) ? bias[colg] : 0.f;
      #pragma unroll
      for (int r=0;r<4;r++){
        int rowg = m0 + wv*(16*RG) + rg*16 + qd*4 + r;
        float v = acc[rg][ct][r];
        if (EPI == 0){ v += bias_v; }
        else if (EPI == 2){ v += bias_v; v = (v > 20.f) ? v : log1pf(expf(v)); }
        outp[(size_t)rowg*ldo + colg] = v;
      }
    }
  }
}

// 4-way partial-K reduce: out[i] = sum_z pp[z*n + i]
__global__ __launch_bounds__(256) void reduce4_kernel(
    const float* __restrict__ pp, float* __restrict__ out, int n)
{
  int i = (blockIdx.x*256 + threadIdx.x)*4;
  if (i >= n) return;
  float4 a = *(const float4*)(pp + i);
  float4 b = *(const float4*)(pp + n + i);
  float4 c = *(const float4*)(pp + 2*(size_t)n + i);
  float4 d = *(const float4*)(pp + 3*(size_t)n + i);
  float4 o;
  o.x = (a.x+b.x)+(c.x+d.x);
  o.y = (a.y+b.y)+(c.y+d.y);
  o.z = (a.z+b.z)+(c.z+d.z);
  o.w = (a.w+b.w)+(c.w+d.w);
  *(float4*)(out + i) = o;
}

// 2-way partial-K reduce + residual: out[i] = p0[i]+p1[i]+r[i]
__global__ __launch_bounds__(256) void reduce2r_kernel(
    const float* __restrict__ p0, const float* __restrict__ p1,
    const float* __restrict__ r, float* __restrict__ out, int n)
{
  int i = (blockIdx.x*256 + threadIdx.x)*4;
  if (i >= n) return;
  float4 a = *(const float4*)(p0 + i);
  float4 b = *(const float4*)(p1 + i);
  float4 c = *(const float4*)(r + i);
  float4 o;
  o.x = a.x+b.x+c.x; o.y = a.y+b.y+c.y; o.z = a.z+b.z+c.z; o.w = a.w+b.w+c.w;
  *(float4*)(out + i) = o;
}

// ---------------------------------------------------------------------------
// LayerNorm over D=1024 -> pre-split hi/lo bf16 (mamba branch)
// ---------------------------------------------------------------------------
__global__ __launch_bounds__(256) void ln_split_kernel(
    const float* __restrict__ x, const float* __restrict__ g, const float* __restrict__ b,
    unsigned short* __restrict__ hi, unsigned short* __restrict__ lo)
{
  int tok = blockIdx.x;
  int tid = threadIdx.x;
  const float* row = x + (size_t)tok * DMODEL;
  float v[4];
  float s = 0.f, sq = 0.f;
  #pragma unroll
  for (int j=0;j<4;j++){
    v[j] = row[j*256 + tid];
    s += v[j]; sq += v[j]*v[j];
  }
  #pragma unroll
  for (int o=1;o<64;o<<=1){ s += __shfl_xor(s,o,64); sq += __shfl_xor(sq,o,64); }
  __shared__ float ss[4], ssq[4];
  int wid = tid >> 6, lane = tid & 63;
  if (lane == 0){ ss[wid]=s; ssq[wid]=sq; }
  __syncthreads();
  s  = ss[0]+ss[1]+ss[2]+ss[3];
  sq = ssq[0]+ssq[1]+ssq[2]+ssq[3];
  float mu = s * (1.f/DMODEL);
  float var = sq * (1.f/DMODEL) - mu*mu;
  float rs = rsqrtf(var + 1e-5f);
  #pragma unroll
  for (int j=0;j<4;j++){
    int d = j*256 + tid;
    float o = (v[j]-mu)*rs*g[d] + b[d];
    unsigned short hu = f2bf(o);
    float hf = __uint_as_float((unsigned int)hu << 16);
    hi[(size_t)tok*DMODEL + d] = hu;
    lo[(size_t)tok*DMODEL + d] = f2bf(o - hf);
  }
}

// ---------------------------------------------------------------------------
// LayerNorm over D=1024 -> fp32 (router) + bf16 (moe_gemm1 A)
// ---------------------------------------------------------------------------
__global__ __launch_bounds__(256) void ln2_kernel(
    const float* __restrict__ x, const float* __restrict__ g, const float* __restrict__ b,
    float* __restrict__ out, unsigned short* __restrict__ outb)
{
  int tok = blockIdx.x;
  int tid = threadIdx.x;
  const float* row = x + (size_t)tok * DMODEL;
  float v[4];
  float s = 0.f, sq = 0.f;
  #pragma unroll
  for (int j=0;j<4;j++){
    v[j] = row[j*256 + tid];
    s += v[j]; sq += v[j]*v[j];
  }
  #pragma unroll
  for (int o=1;o<64;o<<=1){ s += __shfl_xor(s,o,64); sq += __shfl_xor(sq,o,64); }
  __shared__ float ss[4], ssq[4];
  int wid = tid >> 6, lane = tid & 63;
  if (lane == 0){ ss[wid]=s; ssq[wid]=sq; }
  __syncthreads();
  s  = ss[0]+ss[1]+ss[2]+ss[3];
  sq = ssq[0]+ssq[1]+ssq[2]+ssq[3];
  float mu = s * (1.f/DMODEL);
  float var = sq * (1.f/DMODEL) - mu*mu;
  float rs = rsqrtf(var + 1e-5f);
  #pragma unroll
  for (int j=0;j<4;j++){
    int d = j*256 + tid;
    float o = (v[j]-mu)*rs*g[d] + b[d];
    out[(size_t)tok*DMODEL + d] = o;
    outb[(size_t)tok*DMODEL + d] = f2bf(o);
  }
}

// ---------------------------------------------------------------------------
// Causal depthwise conv (KC=4) + SiLU.  xi = xz[:, 0:2048] (row stride 4096)
// ---------------------------------------------------------------------------
__global__ __launch_bounds__(256) void conv_kernel(
    const float* __restrict__ xz, const float* __restrict__ cw,
    const float* __restrict__ cb, float* __restrict__ xc)
{
  int i = blockIdx.x*256 + threadIdx.x;
  int tok = i >> 11;
  int ch  = i & 2047;
  int t   = tok & (TSEQ-1);
  int b   = tok >> 11;
  float acc = cb[ch];
  #pragma unroll
  for (int k=0;k<4;k++){
    int tt = t + k - 3;
    if (tt >= 0)
      acc = fmaf(cw[ch*4 + k], xz[(size_t)((b<<11)+tt)*4096 + ch], acc);
  }
  xc[i] = siluf(acc);
}

// ---------------------------------------------------------------------------
// Chunked parallel selective scan, lane-per-channel (verified round 2).
// ---------------------------------------------------------------------------
__global__ __launch_bounds__(256) void scan_partial(
    const float* __restrict__ xz, const float* __restrict__ xc,
    const float* __restrict__ proj, const float* __restrict__ A_log,
    float* __restrict__ P, float* __restrict__ Q)
{
  int tid = threadIdx.x;
  int ch  = blockIdx.x*256 + tid;
  int c   = blockIdx.y;
  int b   = blockIdx.z;
  float A[16];
  #pragma unroll
  for (int n=0;n<16;n++) A[n] = -expf(A_log[ch*NSTATE + n]);
  float h[16];
  #pragma unroll
  for (int n=0;n<16;n++) h[n] = 0.f;
  float sdt = 0.f;
  int tok0 = (b<<11) + c*CLEN;
  float dtv = xz[(size_t)tok0*4096 + ch];
  float xt  = xc[(size_t)tok0*2048 + ch];
  for (int i=0;i<CLEN;i++){
    int tn = tok0 + ((i+1 < CLEN) ? i+1 : i);
    float dtv_n = xz[(size_t)tn*4096 + ch];
    float xt_n  = xc[(size_t)tn*2048 + ch];
    const float4* pB = (const float4*)(proj + (size_t)(tok0+i)*96 + 64);
    float Bv[16];
    *(float4*)&Bv[0]  = pB[0];
    *(float4*)&Bv[4]  = pB[1];
    *(float4*)&Bv[8]  = pB[2];
    *(float4*)&Bv[12] = pB[3];
    float dxt = dtv*xt;
    sdt += dtv;
    #pragma unroll
    for (int n=0;n<16;n++){
      float dA = __expf(dtv*A[n]);
      h[n] = fmaf(dA, h[n], dxt*Bv[n]);
    }
    dtv = dtv_n; xt = xt_n;
  }
  size_t base = ((((size_t)(b*NCHUNK + c))<<11 | ch)<<4);
  #pragma unroll
  for (int n=0;n<16;n++){
    P[base+n] = __expf(A[n]*sdt);
    Q[base+n] = h[n];
  }
}

__global__ __launch_bounds__(256) void scan_combine(
    const float* __restrict__ Q, float* PH)
{
  int g = blockIdx.x*256 + threadIdx.x;
  int n = g & 15, ch = (g>>4) & 2047, b = g>>15;
  float hs = 0.f;
  for (int c=0;c<NCHUNK;c++){
    size_t idx = ((((size_t)(b*NCHUNK + c))<<11 | ch)<<4) | n;
    float pv = PH[idx];
    float qv = Q[idx];
    PH[idx] = hs;
    hs = fmaf(pv, hs, qv);
  }
}

__global__ __launch_bounds__(256) void scan_final(
    const float* __restrict__ xz, float* __restrict__ xc,
    const float* __restrict__ proj, const float* __restrict__ A_log,
    const float* __restrict__ Dskip, const float* __restrict__ Hs)
{
  int tid = threadIdx.x;
  int ch  = blockIdx.x*256 + tid;
  int c   = blockIdx.y;
  int b   = blockIdx.z;
  float A[16];
  #pragma unroll
  for (int n=0;n<16;n++) A[n] = -expf(A_log[ch*NSTATE + n]);
  float Dv = Dskip[ch];
  size_t base = ((((size_t)(b*NCHUNK + c))<<11 | ch)<<4);
  float h[16];
  #pragma unroll
  for (int n=0;n<16;n++) h[n] = Hs[base+n];
  int tok0 = (b<<11) + c*CLEN;
  float dtv = xz[(size_t)tok0*4096 + ch];
  float xt  = xc[(size_t)tok0*2048 + ch];
  float zv  = xz[(size_t)tok0*4096 + 2048 + ch];
  for (int i=0;i<CLEN;i++){
    int tn = tok0 + ((i+1 < CLEN) ? i+1 : i);
    float dtv_n = xz[(size_t)tn*4096 + ch];
    float xt_n  = xc[(size_t)tn*2048 + ch];
    float zv_n  = xz[(size_t)tn*4096 + 2048 + ch];
    const float4* pB = (const float4*)(proj + (size_t)(tok0+i)*96 + 64);
    float Bv[16], Cv[16];
    *(float4*)&Bv[0]  = pB[0];
    *(float4*)&Bv[4]  = pB[1];
    *(float4*)&Bv[8]  = pB[2];
    *(float4*)&Bv[12] = pB[3];
    *(float4*)&Cv[0]  = pB[4];
    *(float4*)&Cv[4]  = pB[5];
    *(float4*)&Cv[8]  = pB[6];
    *(float4*)&Cv[12] = pB[7];
    float dxt = dtv*xt;
    float y = xt*Dv;
    #pragma unroll
    for (int n=0;n<16;n++){
      float dA = __expf(dtv*A[n]);
      h[n] = fmaf(dA, h[n], dxt*Bv[n]);
      y = fmaf(h[n], Cv[n], y);
    }
    xc[(size_t)(tok0+i)*2048 + ch] = y * siluf(zv);
    dtv = dtv_n; xt = xt_n; zv = zv_n;
  }
}

// ---------------------------------------------------------------------------
// Router (kept precise: top-k decisions are tie-sensitive)
// ---------------------------------------------------------------------------
__global__ __launch_bounds__(256) void router_kernel(
    const float* __restrict__ hmoe, const float* __restrict__ rw,
    float* __restrict__ probs_out, int* __restrict__ cnt,
    int* __restrict__ tok_e0, int* __restrict__ tok_e1,
    float* __restrict__ tok_w0, float* __restrict__ tok_w1)
{
  int tok = blockIdx.x;
  int tid = threadIdx.x;
  int e = tid >> 5, l = tid & 31;
  float s = 0.f;
  const float* row = hmoe + (size_t)tok*DMODEL;
  const float* wr  = rw + (size_t)e*DMODEL;
  for (int d=l; d<DMODEL; d+=32) s = fmaf(row[d], wr[d], s);
  #pragma unroll
  for (int o=1;o<32;o<<=1) s += __shfl_xor(s,o,64);
  __shared__ float lg[8];
  if (l==0) lg[e]=s;
  __syncthreads();
  if (tid==0){
    float mx = lg[0];
    for (int k=1;k<8;k++) mx = fmaxf(mx, lg[k]);
    float pe[8]; float den=0.f;
    for (int k=0;k<8;k++){ pe[k]=expf(lg[k]-mx); den+=pe[k]; }
    float inv = 1.f/den;
    for (int k=0;k<8;k++) probs_out[tok*8+k] = pe[k]*inv;
    int i0=0;
    for (int k=1;k<8;k++) if (pe[k] > pe[i0]) i0=k;
    int i1 = (i0==0)?1:0;
    for (int k=0;k<8;k++) if (k!=i0 && pe[k] > pe[i1]) i1=k;
    float v0=pe[i0], v1=pe[i1], sw=v0+v1;
    tok_e0[tok]=i0; tok_e1[tok]=i1;
    tok_w0[tok]=v0/sw; tok_w1[tok]=v1/sw;
    atomicAdd(&cnt[i0],1); atomicAdd(&cnt[i1],1);
  }
}

__global__ void prefix_kernel(const int* cnt, int* off, int* fill){
  if (threadIdx.x==0){
    int s=0;
    for (int e=0;e<NEXP;e++){ off[e]=s; s+=cnt[e]; fill[e]=0; }
  }
}

__global__ __launch_bounds__(256) void fill_kernel(
    const int* tok_e0, const int* tok_e1, const float* tok_w0, const float* tok_w1,
    const int* off, int* fill, int* slot_tok, float* slot_w)
{
  int tok = blockIdx.x*256 + threadIdx.x;
  int e0=tok_e0[tok], e1=tok_e1[tok];
  int p0 = atomicAdd(&fill[e0],1); int s0 = off[e0]+p0;
  slot_tok[s0]=tok; slot_w[s0]=tok_w0[tok];
  int p1 = atomicAdd(&fill[e1],1); int s1 = off[e1]+p1;
  slot_tok[s1]=tok; slot_w[s1]=tok_w1[tok];
}

// ---------------------------------------------------------------------------
// MoE GEMM1 bf16 MFMA, BM=128 slots x BN=128, LDS dbuf (1 barrier/iter):
// H1 = silu(hn_bf @ w1_bf^T + b1)
// ---------------------------------------------------------------------------
__global__ __launch_bounds__(256) void moe_gemm1(
    const unsigned short* __restrict__ hnb, const unsigned short* __restrict__ w1b,
    const float* __restrict__ b1,
    const int* __restrict__ cnt, const int* __restrict__ off,
    const int* __restrict__ slot_tok, unsigned short* __restrict__ H1)
{
  int e = blockIdx.z;
  int c = cnt[e];
  int r0 = blockIdx.y*128;
  if (r0 >= c) return;
  int base = off[e];
  int tid = threadIdx.x;
  __shared__ int toks[128];
  if (tid < 128) toks[tid] = (r0 + tid < c) ? slot_tok[base + r0 + tid] : -1;
  __shared__ __align__(16) unsigned short As[2*128*40];
  __shared__ __align__(16) unsigned short Ws[2*128*40];
  __syncthreads();

  const int n0   = blockIdx.x*128;
  const int srow = tid >> 1;
  const int sseg = (tid & 1) * 16;
  const int tok  = toks[srow];
  const bool aok = (tok >= 0);
  const unsigned short* Ap = hnb + (size_t)(aok ? tok : 0)*DMODEL + sseg;
  const unsigned short* Wp = w1b + (size_t)e*DFF*DMODEL + (size_t)(n0+srow)*DMODEL + sseg;

  const int lane = tid & 63;
  const int wv   = tid >> 6;
  const int qd   = lane >> 4;
  const int mr   = lane & 15;

  f32x4 acc[2][8];
  #pragma unroll
  for (int rg=0; rg<2; rg++)
    #pragma unroll
    for (int ct=0; ct<8; ct++) acc[rg][ct] = (f32x4){0.f,0.f,0.f,0.f};

  const int ard_o = (wv*32 + mr)*40 + qd*8;
  const int brd_o = mr*40 + qd*8;
  const short8 z8 = {0,0,0,0,0,0,0,0};
  constexpr int HB = 128*40;

  short8 a0, a1, w0, w1v;
  auto load_tile = [&](int kt){
    a0 = aok ? *(const short8*)(Ap + kt)     : z8;
    a1 = aok ? *(const short8*)(Ap + kt + 8) : z8;
    w0 = *(const short8*)(Wp + kt);
    w1v= *(const short8*)(Wp + kt + 8);
  };
  auto store_tile = [&](int b){
    *(short8*)&As[b*HB + srow*40 + sseg]     = a0;
    *(short8*)&As[b*HB + srow*40 + sseg + 8] = a1;
    *(short8*)&Ws[b*HB + srow*40 + sseg]     = w0;
    *(short8*)&Ws[b*HB + srow*40 + sseg + 8] = w1v;
  };

  load_tile(0);
  store_tile(0);
  __syncthreads();
  int cur = 0;
  for (int kt = 0; kt < DMODEL; kt += 32){
    const bool hn = (kt + 32 < DMODEL);
    if (hn) load_tile(kt + 32);
    #pragma unroll
    for (int rg=0; rg<2; rg++){
      short8 af = *(const short8*)&As[cur*HB + ard_o + rg*16*40];
      #pragma unroll
      for (int ct=0; ct<8; ct++){
        short8 bf = *(const short8*)&Ws[cur*HB + brd_o + ct*16*40];
        acc[rg][ct] = __builtin_amdgcn_mfma_f32_16x16x32_bf16(af, bf, acc[rg][ct], 0,0,0);
      }
    }
    if (hn) store_tile(cur ^ 1);
    __syncthreads();
    cur ^= 1;
  }

  #pragma unroll
  for (int rg=0; rg<2; rg++){
    #pragma unroll
    for (int ct=0; ct<8; ct++){
      int colg = n0 + ct*16 + mr;
      float bias = b1[(size_t)e*DFF + colg];
      #pragma unroll
      for (int r=0;r<4;r++){
        int sl = wv*32 + rg*16 + qd*4 + r;
        if (toks[sl] < 0) continue;
        float v = acc[rg][ct][r] + bias;
        H1[(size_t)(base + r0 + sl)*DFF + colg] = f2bf(siluf(v));
      }
    }
  }
}

// ---------------------------------------------------------------------------
// MoE GEMM2 bf16 MFMA, BM=128 x BN=128, LDS dbuf: out += w*(H1 @ w2^T + b2)
// ---------------------------------------------------------------------------
__global__ __launch_bounds__(256) void moe_gemm2(
    const unsigned short* __restrict__ H1, const unsigned short* __restrict__ w2b,
    const float* __restrict__ b2,
    const int* __restrict__ cnt, const int* __restrict__ off,
    const int* __restrict__ slot_tok, const float* __restrict__ slot_w,
    float* __restrict__ hres)
{
  int e = blockIdx.z;
  int c = cnt[e];
  int r0 = blockIdx.y*128;
  if (r0 >= c) return;
  int base = off[e];
  int tid = threadIdx.x;
  __shared__ int toks[128];
  __shared__ float wts[128];
  if (tid < 128){
    int r = r0 + tid;
    toks[tid] = (r<c) ? slot_tok[base+r] : -1;
    wts[tid]  = (r<c) ? slot_w[base+r] : 0.f;
  }
  __shared__ __align__(16) unsigned short As[2*128*40];
  __shared__ __align__(16) unsigned short Ws[2*128*40];
  __syncthreads();

  const int n0   = blockIdx.x*128;
  const int srow = tid >> 1;
  const int sseg = (tid & 1) * 16;
  const bool aok = (toks[srow] >= 0);
  const unsigned short* Ap = H1 + (size_t)(base + r0 + (aok ? srow : 0))*DFF + sseg;
  const unsigned short* Wp = w2b + (size_t)e*DMODEL*DFF + (size_t)(n0+srow)*DFF + sseg;

  const int lane = tid & 63;
  const int wv   = tid >> 6;
  const int qd   = lane >> 4;
  const int mr   = lane & 15;

  f32x4 acc[2][8];
  #pragma unroll
  for (int rg=0; rg<2; rg++)
    #pragma unroll
    for (int ct=0; ct<8; ct++) acc[rg][ct] = (f32x4){0.f,0.f,0.f,0.f};

  const int ard_o = (wv*32 + mr)*40 + qd*8;
  const int brd_o = mr*40 + qd*8;
  const short8 z8 = {0,0,0,0,0,0,0,0};
  constexpr int HB = 128*40;

  short8 a0, a1, w0, w1v;
  auto load_tile = [&](int kt){
    a0 = aok ? *(const short8*)(Ap + kt)     : z8;
    a1 = aok ? *(const short8*)(Ap + kt + 8) : z8;
    w0 = *(const short8*)(Wp + kt);
    w1v= *(const short8*)(Wp + kt + 8);
  };
  auto store_tile = [&](int b){
    *(short8*)&As[b*HB + srow*40 + sseg]     = a0;
    *(short8*)&As[b*HB + srow*40 + sseg + 8] = a1;
    *(short8*)&Ws[b*HB + srow*40 + sseg]     = w0;
    *(short8*)&Ws[b*HB + srow*40 + sseg + 8] = w1v;
  };

  load_tile(0);
  store_tile(0);
  __syncthreads();
  int cur = 0;
  for (int kt = 0; kt < DFF; kt += 32){
    const bool hn = (kt + 32 < DFF);
    if (hn) load_tile(kt + 32);
    #pragma unroll
    for (int rg=0; rg<2; rg++){
      short8 af = *(const short8*)&As[cur*HB + ard_o + rg*16*40];
      #pragma unroll
      for (int ct=0; ct<8; ct++){
        short8 bf = *(const short8*)&Ws[cur*HB + brd_o + ct*16*40];
        acc[rg][ct] = __builtin_amdgcn_mfma_f32_16x16x32_bf16(af, bf, acc[rg][ct], 0,0,0);
      }
    }
    if (hn) store_tile(cur ^ 1);
    __syncthreads();
    cur ^= 1;
  }

  #pragma unroll
  for (int rg=0; rg<2; rg++){
    #pragma unroll
    for (int ct=0; ct<8; ct++){
      int colg = n0 + ct*16 + mr;
      float bias = b2[(size_t)e*DMODEL + colg];
      #pragma unroll
      for (int r=0;r<4;r++){
        int sl = wv*32 + rg*16 + qd*4 + r;
        int t = toks[sl];
        if (t < 0) continue;
        float v = acc[rg][ct][r] + bias;
        atomicAdd(&hres[(size_t)t*DMODEL + colg], wts[sl]*v);
      }
    }
  }
}

// ---------------------------------------------------------------------------
extern "C" void kernel_launch(void* const* d_in, const int* in_sizes, int n_in,
                              void* d_out, int out_size, void* d_ws, size_t ws_size,
                              hipStream_t stream)
{
  const float* x         = (const float*)d_in[0];
  const float* ln_m_g    = (const float*)d_in[1];
  const float* ln_m_b    = (const float*)d_in[2];
  const float* ln_e_g    = (const float*)d_in[3];
  const float* ln_e_b    = (const float*)d_in[4];
  const float* in_proj_w = (const float*)d_in[5];
  const float* in_proj_b = (const float*)d_in[6];
  const float* conv_w    = (const float*)d_in[7];
  const float* conv_b    = (const float*)d_in[8];
  const float* x_proj_w  = (const float*)d_in[9];
  const float* dt_proj_w = (const float*)d_in[10];
  const float* dt_proj_b = (const float*)d_in[11];
  const float* A_log     = (const float*)d_in[12];
  const float* D_skip    = (const float*)d_in[13];
  const float* out_proj_w= (const float*)d_in[14];
  const float* router_w  = (const float*)d_in[15];
  const float* w1        = (const float*)d_in[16];
  const float* b1        = (const float*)d_in[17];
  const float* w2        = (const float*)d_in[18];
  const float* b2        = (const float*)d_in[19];

  // ws timeline:
  //   [0,64M)  xz (in_proj out; xi half rewritten by dt; scans consume)
  //            -> after scan_final: hn fp32 [0,16M); out_proj partials
  //               p0 [16M,32M) p1 [32M,48M) -> H1 bf16 [16M,48M);
  //               hn_bf [48M,56M)
  //   [64M,96M) Wi hi/lo (pre-conv) -> xc -> wmoe (w1_bf then w2_bf)
  //   [96M,97.5M) proj ; [97.5M,..) misc
  // d_out timeline:
  //   hn_hi [0,8M) hn_lo [8,16M) -> Wx/Wd [0,1.31M) + x_proj partials
  //   [2M,8.3M) -> P [0,8.39M) Q [8.39,16.78M) -> Wo [8.39M,16.39M)
  //   -> out_h [0,16M) (reduce2r; moe_gemm2 atomics) + probs [16.78M,..)
  char* ws = (char*)d_ws;
  float* xz   = (float*)(ws + 0);
  float* xc   = (float*)(ws + 67108864ull);
  float* proj = (float*)(ws + 100663296ull);
  char*  misc = ws + 102236160ull;
  float* hn   = (float*)(ws + 0);                               // post-scan
  float* pout = (float*)(ws + 16777216ull);                     // out_proj partials (2x16MB)
  unsigned short* H1    = (unsigned short*)(ws + 16777216ull);
  unsigned short* hn_bf = (unsigned short*)(ws + 50331648ull);
  unsigned short* wmoe  = (unsigned short*)(ws + 67108864ull);

  unsigned short* hn_hi = (unsigned short*)d_out;               // [0,8M)
  unsigned short* hn_lo = hn_hi + 4194304;                      // [8M,16M)
  float* Pbuf = (float*)d_out;                                  // 2M floats
  float* Qbuf = (float*)d_out + (2u<<20);                       // 2M floats
  float* ppx  = (float*)((char*)d_out + 2097152ull);            // x_proj partials 4x1.57MB

  unsigned short* Wi_hi = (unsigned short*)(ws + 67108864ull);
  unsigned short* Wi_lo = Wi_hi + 4194304;
  unsigned short* Wo_hi = (unsigned short*)Qbuf;                // d_out [8.39M,16.39M)
  unsigned short* Wo_lo = Wo_hi + 2097152;
  unsigned short* Wx_hi = (unsigned short*)d_out;
  unsigned short* Wx_lo = Wx_hi + 196608;
  unsigned short* Wd_hi = Wx_lo + 196608;
  unsigned short* Wd_lo = Wd_hi + 131072;

  int*   cnt      = (int*)(misc);
  int*   fill     = (int*)(misc + 64);
  int*   offp     = (int*)(misc + 128);
  int*   tok_e0   = (int*)(misc + 1024);
  int*   tok_e1   = (int*)(misc + 1024 + 16384);
  float* tok_w0   = (float*)(misc + 1024 + 32768);
  float* tok_w1   = (float*)(misc + 1024 + 49152);
  int*   slot_tok = (int*)(misc + 1024 + 65536);
  float* slot_w   = (float*)(misc + 1024 + 98304);
  float* out_h    = (float*)d_out;
  float* probs_out= (float*)d_out + 4194304;

  zero_kernel<<<1, 64, 0, stream>>>(cnt);

  // ---- Mamba branch ----
  split_kernel<<<4096, 256, 0, stream>>>(in_proj_w, Wi_hi, Wi_lo, 4194304);
  ln_split_kernel<<<NTOK, 256, 0, stream>>>(x, ln_m_g, ln_m_b, hn_hi, hn_lo);
  // in_proj: BM=128 x BN=128 (CT=8), dbuf pipeline
  gemm_big<0,128,true,8,false><<<dim3(32, 32), 256, 0, stream>>>(
      nullptr, hn_hi, hn_lo, DMODEL, Wi_hi, Wi_lo, DMODEL, NTOK, 4096, DMODEL,
      in_proj_b, xz, 4096);
  split_kernel<<<192, 256, 0, stream>>>(x_proj_w, Wx_hi, Wx_lo, 196608);
  split_kernel<<<128, 256, 0, stream>>>(dt_proj_w, Wd_hi, Wd_lo, 131072);
  conv_kernel<<<NTOK*DINNER/256, 256, 0, stream>>>(xz, conv_w, conv_b, xc);
  // x_proj: split-K=4 (K=512/slice), BM=64 x BN=128, grid 256
  gemm_big<1,64,false,8,true><<<dim3(1, 64, 4), 256, 0, stream>>>(
      xc, nullptr, nullptr, DINNER, Wx_hi, Wx_lo, DINNER, NTOK, 96, 512,
      nullptr, ppx, 96);
  reduce4_kernel<<<384, 256, 0, stream>>>(ppx, proj, NTOK*96);
  gemm_big<2,128,false,8,false><<<dim3(16, 32), 256, 0, stream>>>(
      proj, nullptr, nullptr, 96, Wd_hi, Wd_lo, DTRANK, NTOK, DINNER, DTRANK,
      dt_proj_b, xz, 4096);
  scan_partial<<<dim3(DINNER/256, NCHUNK, 2), 256, 0, stream>>>(
      xz, xc, proj, A_log, Pbuf, Qbuf);
  scan_combine<<<256, 256, 0, stream>>>(Qbuf, Pbuf);
  scan_final<<<dim3(DINNER/256, NCHUNK, 2), 256, 0, stream>>>(
      xz, xc, proj, A_log, D_skip, Pbuf);
  // out_proj: split-K=2 (K=1024/slice), grid 512; Wo in dead Qbuf
  split_kernel<<<2048, 256, 0, stream>>>(out_proj_w, Wo_hi, Wo_lo, 2097152);
  gemm_big<1,128,false,8,true><<<dim3(8, 32, 2), 256, 0, stream>>>(
      xc, nullptr, nullptr, DINNER, Wo_hi, Wo_lo, DINNER, NTOK, DMODEL, 1024,
      nullptr, pout, DMODEL);
  // h = p0 + p1 + x  -> final output region directly
  reduce2r_kernel<<<4096, 256, 0, stream>>>(pout, pout + 4194304, x, out_h,
                                            NTOK*DMODEL);

  // ---- MoE branch ----
  ln2_kernel<<<NTOK, 256, 0, stream>>>(out_h, ln_e_g, ln_e_b, hn, hn_bf);
  router_kernel<<<NTOK, 256, 0, stream>>>(hn, router_w, probs_out, cnt,
                                          tok_e0, tok_e1, tok_w0, tok_w1);
  prefix_kernel<<<1, 64, 0, stream>>>(cnt, offp, fill);
  fill_kernel<<<NTOK/256, 256, 0, stream>>>(tok_e0, tok_e1, tok_w0, tok_w1,
                                            offp, fill, slot_tok, slot_w);
  cvt_bf_kernel<<<8192, 256, 0, stream>>>(w1, wmoe, NEXP*DFF*DMODEL);
  moe_gemm1<<<dim3(DFF/128, 32, NEXP), 256, 0, stream>>>(
      hn_bf, wmoe, b1, cnt, offp, slot_tok, H1);
  cvt_bf_kernel<<<8192, 256, 0, stream>>>(w2, wmoe, NEXP*DMODEL*DFF);
  moe_gemm2<<<dim3(DMODEL/128, 32, NEXP), 256, 0, stream>>>(
      H1, wmoe, b2, cnt, offp, slot_tok, slot_w, out_h);
}